// Round 13
// baseline (823.346 us; speedup 1.0000x reference)
//
#include <hip/hip_runtime.h>
#include <hip/hip_bf16.h>

#define SS   50     // sequence length
#define DD   300    // embedding dim
#define NH   15     // heads
#define HD   20     // per-head dim
#define QDIM 200    // additive attention dim

// ws (bf16 elements): 5 proj [304][320] + Wa [208][320]
#define WSEG  97280
#define WAOFF 486400
#define WTOT  552960

typedef __attribute__((ext_vector_type(8)))  short bf8t;
typedef __attribute__((ext_vector_type(4)))  float f4t;
typedef __attribute__((ext_vector_type(16))) float f16t;

__device__ __forceinline__ float bflo(unsigned p){ return __uint_as_float(p << 16); }
__device__ __forceinline__ float bfhi(unsigned p){ return __uint_as_float(p & 0xffff0000u); }
__device__ __forceinline__ unsigned short f2bf(float x){
  unsigned u = __float_as_uint(x);
  return (unsigned short)((u + 0x7fffu + ((u >> 16) & 1u)) >> 16);
}
__device__ __forceinline__ unsigned packbf(float a, float b){
  return (unsigned)f2bf(a) | ((unsigned)f2bf(b) << 16);
}
__device__ __forceinline__ f16t zero16(){
  f16t v;
  #pragma unroll
  for (int i = 0; i < 16; ++i) v[i] = 0.f;
  return v;
}

// ---------------- weight converter: f32 [300][N] -> bf16 [Npad][320] (B^T, zero-padded)
__global__ __launch_bounds__(256) void conv_weights(
    const float* __restrict__ Wq, const float* __restrict__ Wk,
    const float* __restrict__ Wv, const float* __restrict__ Wqp,
    const float* __restrict__ Wkp, const float* __restrict__ Wa,
    short* __restrict__ ws)
{
  int idx = blockIdx.x*256 + threadIdx.x;
  if (idx >= WTOT) return;
  float v = 0.f;
  if (idx < WAOFF){
    int seg = idx / WSEG, r = idx - seg*WSEG;
    int n = r / 320, k = r - n*320;
    const float* W = (seg==0)?Wq:(seg==1)?Wk:(seg==2)?Wv:(seg==3)?Wqp:Wkp;
    if (n < DD && k < DD) v = W[k*DD + n];
  } else {
    int r = idx - WAOFF;
    int n = r / 320, k = r - n*320;
    if (n < QDIM && k < DD) v = Wa[k*QDIM + n];
  }
  ws[idx] = (short)f2bf(v);
}

// ============================ K0: ue gather -> bf16 [M][320] =================
__global__ __launch_bounds__(512) void k0_gather(
    const int* __restrict__ ids, const float* __restrict__ emb,
    short* __restrict__ a2)
{
  __shared__ int sid[SS];
  const int tid = threadIdx.x, b = blockIdx.x;
  if (tid < SS) sid[tid] = ids[(size_t)b*SS + tid];
  __syncthreads();
  for (int i = tid; i < SS*160; i += 512){
    int s = i/160, j2 = i - s*160;          // j2-th u32 (2 elems), 160/row
    unsigned v = 0;
    if (j2 < 150){
      float2 t = *(const float2*)(emb + (size_t)sid[s]*DD + j2*2);
      v = packbf(t.x, t.y);
    }
    *(unsigned*)(a2 + ((size_t)b*SS + s)*320 + j2*2) = v;
  }
}

// ============================ K1: tiled GEMM (B-stage amortized 8x) ==========
// Block = (slab, M-supertile of 1024 rows). 25 slabs x msuper blocks.
// Bijective XCD mapping (m204) keeps one supertile's 25 slabs on one XCD.
// Stage B slab ONCE (40KB LDS, stride 656), single barrier, then 8 sub-tiles:
// per-lane A strip (K=320) -> 10 uint4 regs from L2, 40 ds_read+MFMA, store.
// seg 0,1,2: A = uv f32 (convert in-lane); seg 3,4: A = a2 bf16.
#define G_SM  41984

__global__ __launch_bounds__(512, 4) void k1_gemm(
    const float* __restrict__ uv, const short* __restrict__ a2,
    const short* __restrict__ wsb,
    const float* __restrict__ bq, const float* __restrict__ bk,
    const float* __restrict__ bv, const float* __restrict__ bqp,
    const float* __restrict__ bkp,
    short* __restrict__ qc, short* __restrict__ kc, short* __restrict__ vv,
    short* __restrict__ qp, short* __restrict__ kp,
    int msuper, int M)
{
  __shared__ __align__(16) unsigned char sm[G_SM];
  const int tid = threadIdx.x;
  const int bid = blockIdx.x;
  const int nwg = 25*msuper;
  // m204 bijective XCD swizzle: consecutive wg on one XCD
  const int q8 = nwg >> 3, r8 = nwg & 7;
  const int xcd = bid & 7;
  const int wg  = (xcd < r8 ? xcd*(q8+1) : r8*(q8+1) + (xcd - r8)*q8) + (bid >> 3);
  const int stile = wg / 25;
  const int slab  = wg - stile*25;
  const int seg  = slab / 5;
  const int col0 = (slab - seg*5)*64;
  const int row0 = stile*1024;

  // ---- stage B slab once: 64 cols x 640B = 2560 x 16B chunks ----
  const short* bsrc = wsb + (size_t)seg*WSEG + (size_t)col0*320;
  for (int i = tid; i < 2560; i += 512){
    int c = i/40, k8 = i - c*40;
    *(float4*)(sm + (unsigned)c*656 + (unsigned)k8*16) =
        *(const float4*)(bsrc + (size_t)c*320 + k8*8);
  }
  __syncthreads();                          // B slab visible; the ONLY barrier
  __builtin_amdgcn_sched_barrier(0);        // pin: nothing crosses the barrier

  const int w = tid >> 6, lane = tid & 63;
  const int lm = lane & 15, lg = lane >> 4;
  const bool segA2 = (seg >= 3);
  const float* bias = (seg==0)?bq:(seg==1)?bk:(seg==2)?bv:(seg==3)?bqp:bkp;
  short* outp = (seg==0)?qc:(seg==1)?kc:(seg==2)?vv:(seg==3)?qp:kp;

  #pragma unroll 1
  for (int g = 0; g < 8; ++g){
    // ---- preload this wave's A strip: row = row0+g*128+w*16+lm, k = st*32+lg*8
    int rowA = row0 + g*128 + w*16 + lm; if (rowA > M-1) rowA = M-1;
    uint4 a[10];
    if (segA2){
      const short* ap = a2 + (size_t)rowA*320 + lg*8;
      #pragma unroll
      for (int st = 0; st < 10; ++st)
        a[st] = *(const uint4*)(ap + st*32);
    } else {
      const float* up = uv + (size_t)rowA*DD;
      #pragma unroll
      for (int st = 0; st < 10; ++st){
        int k0e = st*32 + lg*8;
        float v[8];
        if (k0e + 8 <= DD){
          float4 p = *(const float4*)(up + k0e);
          float4 q = *(const float4*)(up + k0e + 4);
          v[0]=p.x; v[1]=p.y; v[2]=p.z; v[3]=p.w;
          v[4]=q.x; v[5]=q.y; v[6]=q.z; v[7]=q.w;
        } else {
          #pragma unroll
          for (int j = 0; j < 8; ++j){
            int kk = k0e + j;
            v[j] = (kk < DD) ? up[kk] : 0.f;
          }
        }
        a[st] = (uint4){ packbf(v[0],v[1]), packbf(v[2],v[3]),
                         packbf(v[4],v[5]), packbf(v[6],v[7]) };
      }
    }

    // ---- barrier-free K-loop: 10 x {4 B ds_reads, 4 MFMA} (B is read-only)
    f4t acc[4];
    #pragma unroll
    for (int nt = 0; nt < 4; ++nt) acc[nt] = (f4t){0.f,0.f,0.f,0.f};
    #pragma unroll
    for (int st = 0; st < 10; ++st){
      bf8t af = *(const bf8t*)&a[st];
      #pragma unroll
      for (int nt = 0; nt < 4; ++nt){
        bf8t bfrag = *(const bf8t*)(sm + (unsigned)(nt*16 + lm)*656 + (unsigned)(st*64 + lg*16));
        acc[nt] = __builtin_amdgcn_mfma_f32_16x16x32_bf16(af, bfrag, acc[nt], 0, 0, 0);
      }
    }

    // ---- epilogue: bias + bf16 store to natural [M][300] ----
    #pragma unroll
    for (int nt = 0; nt < 4; ++nt){
      int colseg = col0 + nt*16 + lm;
      if (colseg < DD){
        float bb = bias[colseg];
        #pragma unroll
        for (int i = 0; i < 4; ++i){
          int row = row0 + g*128 + w*16 + lg*4 + i;
          if (row < M) outp[(size_t)row*DD + colseg] = (short)f2bf(acc[nt][i] + bb);
        }
      }
    }
  }
}

// ============================ K2: attention ==================================
// block = (b, head-group hg of <=4 heads). LDS:
//   Q [50][192]bf16 stride400 @0 ([Qc20|Qp20|8z] per head)
//   K @20000 ([Ksum20|Kc20|8z], Ksum = Kc+Kp)
//   VT [92][64keys]bf16 stride144 @40000 ; P overlays Q/K: per-wave [32][64] @ w*4608
#define A_Q   0
#define A_K   20000
#define A_VT  40000
#define A_PBLK 4608
#define A_SM  53248

__global__ __launch_bounds__(512) void k2_attn(
    const short* __restrict__ qcg, const short* __restrict__ qpg,
    const short* __restrict__ kcg, const short* __restrict__ kpg,
    const short* __restrict__ vg,  short* __restrict__ cg)
{
  __shared__ __align__(16) unsigned char sm[A_SM];
  const int tid  = threadIdx.x;
  const int bid  = blockIdx.x;
  const int b    = bid >> 2;
  const int hg   = bid & 3;
  const int nheads = (hg < 3) ? 4 : 3;
  const int w    = tid >> 6;
  const int lane = tid & 63;
  const int l31  = lane & 31, hi = lane >> 5;

  // zero VT (keys>=50 must be 0; rows 80..91 finite)
  for (int i = tid; i < 828; i += 512)
    *(float4*)(sm + A_VT + (unsigned)i*16) = make_float4(0.f,0.f,0.f,0.f);
  __syncthreads();
  // stage Q: per (row,hl): [Qc20|Qp20|pad8] (src col clamped for head 15)
  for (int i = tid; i < 4800; i += 512){
    int rhd = i / 24, j = i - rhd*24;
    int row = rhd >> 2, hl = rhd & 3;
    int hc = (hg*4 + hl)*20; if (hc > 280) hc = 280;
    const size_t rbase = ((size_t)b*SS + row)*(size_t)DD + hc;
    unsigned char* ldst = sm + A_Q + (unsigned)row*400 + (unsigned)hl*96;
    if (j < 10)      *(unsigned*)(ldst + j*4)           = *(const unsigned*)(qcg + rbase + j*2);
    else if (j < 20) *(unsigned*)(ldst + 40 + (j-10)*4) = *(const unsigned*)(qpg + rbase + (j-10)*2);
    else             *(unsigned*)(ldst + 80 + (j-20)*4) = 0u;
  }
  // stage K: [Ksum20|Kc20|pad8]
  for (int i = tid; i < 4800; i += 512){
    int rhd = i / 24, j = i - rhd*24;
    int row = rhd >> 2, hl = rhd & 3;
    int hc = (hg*4 + hl)*20; if (hc > 280) hc = 280;
    const size_t rbase = ((size_t)b*SS + row)*(size_t)DD + hc;
    unsigned char* ldst = sm + A_K + (unsigned)row*400 + (unsigned)hl*96;
    if (j < 10){
      unsigned c = *(const unsigned*)(kcg + rbase + j*2);
      unsigned p = *(const unsigned*)(kpg + rbase + j*2);
      *(unsigned*)(ldst + j*4) = packbf(bflo(c)+bflo(p), bfhi(c)+bfhi(p));
    } else if (j < 20){
      *(unsigned*)(ldst + 40 + (j-10)*4) = *(const unsigned*)(kcg + rbase + (j-10)*2);
    } else {
      *(unsigned*)(ldst + 80 + (j-20)*4) = 0u;
    }
  }
  // stage VT (transpose): u32 (2 dims) per (row,d2); src col clamped
  for (int i = tid; i < 2000; i += 512){
    int row = i/40, d2 = i - row*40;
    int col = hg*80 + d2*2; if (col > 298) col = 298;
    unsigned v = *(const unsigned*)(vg + ((size_t)b*SS + row)*(size_t)DD + col);
    *(unsigned short*)(sm + A_VT + (unsigned)(d2*2)*144   + (unsigned)row*2) = (unsigned short)(v & 0xffffu);
    *(unsigned short*)(sm + A_VT + (unsigned)(d2*2+1)*144 + (unsigned)row*2) = (unsigned short)(v >> 16);
  }
  __syncthreads();

  const float rscale = 0.1290994449f;  // 1/sqrt(3*DK)
  const int ahl = w >> 1, rt = w & 1;
  const bool act = (ahl < nheads);
  f16t s0, s1;
  if (act){
    s0 = zero16(); s1 = zero16();
    unsigned aoff = A_Q + (unsigned)(rt*32 + l31)*400 + (unsigned)ahl*96 + (unsigned)hi*16;
    unsigned koff = A_K + (unsigned)l31*400 + (unsigned)ahl*96 + (unsigned)hi*16;
    #pragma unroll
    for (int ks = 0; ks < 3; ++ks){
      bf8t a  = *(const bf8t*)(sm + aoff + ks*32);
      bf8t b0 = *(const bf8t*)(sm + koff + ks*32);
      bf8t b1 = *(const bf8t*)(sm + koff + 32u*400 + ks*32);
      s0 = __builtin_amdgcn_mfma_f32_32x32x16_bf16(a, b0, s0, 0, 0, 0);
      s1 = __builtin_amdgcn_mfma_f32_32x32x16_bf16(a, b1, s1, 0, 0, 0);
    }
  }
  __syncthreads();   // Q/K reads done -> P may overwrite
  if (act){
    const bool m1 = (l31 >= 18);   // key 32+l31 >= 50
    unsigned pb = (unsigned)w*A_PBLK;
    float rinv[16];
    #pragma unroll
    for (int r = 0; r < 16; ++r){
      int lrow = (r&3) + 8*(r>>2) + 4*hi;
      float v0 = s0[r]*rscale;
      float v1 = m1 ? -INFINITY : s1[r]*rscale;
      float mx = fmaxf(v0, v1);
      #pragma unroll
      for (int off = 1; off <= 16; off <<= 1) mx = fmaxf(mx, __shfl_xor(mx, off));
      float e0 = __expf(v0 - mx);
      float e1 = m1 ? 0.f : __expf(v1 - mx);
      float sum = e0 + e1;
      #pragma unroll
      for (int off = 1; off <= 16; off <<= 1) sum += __shfl_xor(sum, off);
      rinv[r] = 1.0f/sum;
      *(unsigned short*)(sm + pb + (unsigned)lrow*144 + (unsigned)l31*2)      = f2bf(e0);
      *(unsigned short*)(sm + pb + (unsigned)lrow*144 + 64 + (unsigned)l31*2) = f2bf(e1);
    }
    f16t c = zero16();
    unsigned pa  = pb + (unsigned)l31*144 + (unsigned)hi*16;
    unsigned vb2 = A_VT + (unsigned)(ahl*HD + l31)*144 + (unsigned)hi*16;
    #pragma unroll
    for (int ks = 0; ks < 4; ++ks){
      bf8t a = *(const bf8t*)(sm + pa + ks*32);
      bf8t v = *(const bf8t*)(sm + vb2 + ks*32);
      c = __builtin_amdgcn_mfma_f32_32x32x16_bf16(a, v, c, 0, 0, 0);
    }
    if (l31 < HD){
      int h = hg*4 + ahl;
      #pragma unroll
      for (int r = 0; r < 16; ++r){
        int q = rt*32 + (r&3) + 8*(r>>2) + 4*hi;
        if (q < SS)
          cg[((size_t)b*SS + q)*DD + h*HD + l31] = (short)f2bf(c[r]*rinv[r]);
      }
    }
  }
}

// ============================ K3: pooling ====================================
#define B_CTX 0
#define B_LG  41984
#define B_A2  44032
#define B_SM  44288

template<int NT, int NCTM>
__device__ __forceinline__ void gemm10(const unsigned char* sm, unsigned abase,
                                       const short* __restrict__ wt,
                                       int lane, int w, f4t (&acc)[NT][4])
{
  const int lm = lane & 15, lg = lane >> 4;
  #pragma unroll
  for (int step = 0; step < 10; ++step){
    bf8t a[4];
    #pragma unroll
    for (int rt = 0; rt < 4; ++rt)
      a[rt] = *(const bf8t*)(sm + abase + (unsigned)(rt*16 + lm)*656u + (unsigned)(step*32 + lg*8)*2u);
    #pragma unroll
    for (int t = 0; t < NT; ++t){
      int ct = w + t*8; if (ct > NCTM) ct = NCTM;
      bf8t bb = *(const bf8t*)(wt + (size_t)(ct*16 + lm)*320 + step*32 + lg*8);
      #pragma unroll
      for (int rt = 0; rt < 4; ++rt)
        acc[t][rt] = __builtin_amdgcn_mfma_f32_16x16x32_bf16(a[rt], bb, acc[t][rt], 0, 0, 0);
    }
  }
}

__global__ __launch_bounds__(512) void k3_pool(
    const short* __restrict__ cg, const short* __restrict__ wsb,
    const float* __restrict__ ba, const float* __restrict__ qa,
    float* __restrict__ out)
{
  __shared__ __align__(16) unsigned char sm[B_SM];
  const int tid  = threadIdx.x;
  const int b    = blockIdx.x;
  const int w    = tid >> 6;
  const int lane = tid & 63;
  const int lm   = lane & 15, lg = lane >> 4;
  const short* waT = wsb + WAOFF;

  for (int i = tid; i < SS*75; i += 512){
    int row = i/75, c = i - row*75;
    uint2 v = *(const uint2*)(cg + ((size_t)b*SS + row)*DD + c*4);
    *(uint2*)(sm + B_CTX + (unsigned)row*656 + (unsigned)c*8) = v;
  }
  for (int i = tid; i < SS*14; i += 512)
    *(unsigned*)(sm + B_CTX + (unsigned)(i/14)*656 + 600u + (unsigned)(i%14)*4) = 0;
  __syncthreads();

  {
    f4t accp[2][4];
    #pragma unroll
    for (int t = 0; t < 2; ++t)
      #pragma unroll
      for (int r = 0; r < 4; ++r) accp[t][r] = (f4t){0.f,0.f,0.f,0.f};
    gemm10<2,12>(sm, B_CTX, waT, lane, w, accp);
    float part[4][4];
    #pragma unroll
    for (int rt2 = 0; rt2 < 4; ++rt2)
      #pragma unroll
      for (int i = 0; i < 4; ++i) part[rt2][i] = 0.f;
    #pragma unroll
    for (int t = 0; t < 2; ++t){
      int ct = w + t*8; if (ct > 12) ct = 12;
      bool valid = (t == 0) || (w < 5);
      int col = ct*16 + lm;
      float bav = (col < QDIM) ? ba[col] : 0.f;
      float qav = (valid && col < QDIM) ? qa[col] : 0.f;
      #pragma unroll
      for (int rt2 = 0; rt2 < 4; ++rt2)
        #pragma unroll
        for (int i = 0; i < 4; ++i)
          part[rt2][i] += tanhf(accp[t][rt2][i] + bav) * qav;
    }
    #pragma unroll
    for (int off = 1; off <= 8; off <<= 1)
      #pragma unroll
      for (int rt2 = 0; rt2 < 4; ++rt2)
        #pragma unroll
        for (int i = 0; i < 4; ++i)
          part[rt2][i] += __shfl_xor(part[rt2][i], off);
    if (lm == 0){
      #pragma unroll
      for (int rt2 = 0; rt2 < 4; ++rt2)
        #pragma unroll
        for (int i = 0; i < 4; ++i){
          int row = rt2*16 + lg*4 + i;
          if (row < SS) *(float*)(sm + B_LG + (unsigned)(row*8 + w)*4) = part[rt2][i];
        }
    }
  }
  __syncthreads();
  if (w == 0){
    const int sl = lane < SS ? lane : SS - 1;
    const bool rowok = lane < SS;
    float lgv = -INFINITY;
    if (rowok){
      float s = 0.f;
      #pragma unroll
      for (int j = 0; j < 8; ++j) s += *(const float*)(sm + B_LG + (unsigned)(sl*8 + j)*4);
      lgv = s;
    }
    float m = lgv;
    #pragma unroll
    for (int off = 32; off; off >>= 1) m = fmaxf(m, __shfl_xor(m, off));
    float e = rowok ? __expf(lgv - m) : 0.f;
    float ssum = e;
    #pragma unroll
    for (int off = 32; off; off >>= 1) ssum += __shfl_xor(ssum, off);
    *(float*)(sm + B_A2 + lane*4) = e / ssum;
  }
  __syncthreads();
  if (tid < DD){
    float accv = 0.f;
    for (int s = 0; s < SS; ++s){
      float av = *(const float*)(sm + B_A2 + (unsigned)s*4);
      unsigned short cv = *(const unsigned short*)(sm + B_CTX + (unsigned)s*656 + (unsigned)tid*2);
      accv = fmaf(av, __uint_as_float((unsigned)cv << 16), accv);
    }
    out[(size_t)b*DD + tid] = accv;
  }
}

// ===================== fallback: round-4 fused kernel ========================
#define OFF_UV  0
#define OFF_UE  32800
#define QKSTR   400
#define OFF_Q   65600
#define OFF_K   85600
#define OFF_P   65600
#define PBLK    4608
#define PSTR    144
#define VTSTR   144
#define OFF_VT  105600
#define OFF_CTX 117120
#define OFF_LG  159104
#define OFF_A2  161152
#define OFF_IDS 161408
#define SM_TOTAL 161616

__global__ __launch_bounds__(512) void user_enc_kernel(
    const int*   __restrict__ ids, const float* __restrict__ uv,
    const float* __restrict__ emb,
    const float* __restrict__ bq, const float* __restrict__ bk,
    const float* __restrict__ bv, const float* __restrict__ bqp,
    const float* __restrict__ bkp,
    const float* __restrict__ ba, const float* __restrict__ qa,
    const short* __restrict__ wsb, float* __restrict__ out)
{
  __shared__ __align__(16) unsigned char sm[SM_TOTAL];
  const int tid  = threadIdx.x;
  const int b    = blockIdx.x;
  const int w    = tid >> 6;
  const int lane = tid & 63;
  const int lm   = lane & 15, lg = lane >> 4;
  const int l31  = lane & 31, hi = lane >> 5;

  const short* wqT  = wsb;
  const short* wkT  = wsb + WSEG;
  const short* wvT  = wsb + 2*WSEG;
  const short* wqpT = wsb + 3*WSEG;
  const short* wkpT = wsb + 4*WSEG;
  const short* waT  = wsb + WAOFF;

  if (tid < SS) *(int*)(sm + OFF_IDS + tid*4) = ids[(size_t)b*SS + tid];
  {
    const float* srcv = uv + (size_t)b*SS*DD;
    for (int i = tid; i < SS*75; i += 512){
      int s = i/75, j4 = i - s*75;
      float4 v = *(const float4*)(srcv + s*DD + j4*4);
      *(unsigned*)(sm + OFF_UV + (unsigned)s*656 + (unsigned)j4*8)     = packbf(v.x, v.y);
      *(unsigned*)(sm + OFF_UV + (unsigned)s*656 + (unsigned)j4*8 + 4) = packbf(v.z, v.w);
    }
    for (int i = tid; i < SS*28; i += 512){
      int s = i/28, j = i - s*28;
      unsigned off = (j < 14) ? (OFF_UV + (unsigned)s*656 + 600u + (unsigned)j*4)
                              : (OFF_UE + (unsigned)s*656 + 600u + (unsigned)(j-14)*4);
      *(unsigned*)(sm + off) = 0;
    }
    for (int i = tid; i < SS*14; i += 512)
      *(unsigned*)(sm + OFF_CTX + (unsigned)(i/14)*656 + 600u + (unsigned)(i%14)*4) = 0;
    for (int i = tid; i < 720; i += 512)
      *(float4*)(sm + OFF_VT + (unsigned)i*16) = make_float4(0.f,0.f,0.f,0.f);
  }
  __syncthreads();
  for (int i = tid; i < SS*75; i += 512){
    int s = i/75, j4 = i - s*75;
    int id = *(const int*)(sm + OFF_IDS + s*4);
    float4 v = *(const float4*)(emb + (size_t)id*DD + j4*4);
    *(unsigned*)(sm + OFF_UE + (unsigned)s*656 + (unsigned)j4*8)     = packbf(v.x, v.y);
    *(unsigned*)(sm + OFF_UE + (unsigned)s*656 + (unsigned)j4*8 + 4) = packbf(v.z, v.w);
  }

  const float rscale = 0.1290994449f;
  #pragma unroll 1
  for (int nb4 = 0; nb4 < 4; ++nb4){
    const int nheads = (nb4 < 3) ? 4 : 3;
    const int NCT    = (nb4 < 3) ? 5 : 4;
    __syncthreads();
    for (int i = tid; i < SS*4; i += 512){
      int r = i >> 2, hl0 = i & 3;
      *(float4*)(sm + OFF_Q + (unsigned)r*QKSTR + (unsigned)hl0*96 + 80) = make_float4(0.f,0.f,0.f,0.f);
      *(float4*)(sm + OFF_K + (unsigned)r*QKSTR + (unsigned)hl0*96 + 80) = make_float4(0.f,0.f,0.f,0.f);
    }
    for (int ht = w; ht < 8*NCT; ht += 8){
      const int g   = (ht >= 6*NCT) ? 3 : (ht >= 4*NCT) ? 2 : (ht >= 2*NCT) ? 1 : 0;
      const int rem = ht - g*2*NCT;
      const int c   = rem >> 1, rh = rem & 1;
      const int col = nb4*80 + c*16 + lm;
      const int colc = (col < DD) ? col : DD-1;
      const int head = col / HD;
      const int dd   = col - head*HD;
      const int hl   = head - nb4*4;
      const bool valid = (hl < nheads) && (col < DD);
      const unsigned abase = (g == 1) ? (unsigned)OFF_UE : (unsigned)OFF_UV;
      const short* wt = (g==0) ? wqT : (g==1) ? wqpT : (g==2) ? wvT : wkT;
      const short* wb = wt + (size_t)col*320 + lg*8;
      f4t a0 = {0.f,0.f,0.f,0.f}, a1 = {0.f,0.f,0.f,0.f};
      #pragma unroll
      for (int st = 0; st < 10; ++st){
        bf8t bb = *(const bf8t*)(wb + st*32);
        bf8t x0 = *(const bf8t*)(sm + abase + (unsigned)(rh*32 + lm)*656u + (unsigned)(st*32 + lg*8)*2u);
        bf8t x1 = *(const bf8t*)(sm + abase + (unsigned)(rh*32 + 16 + lm)*656u + (unsigned)(st*32 + lg*8)*2u);
        a0 = __builtin_amdgcn_mfma_f32_16x16x32_bf16(x0, bb, a0, 0, 0, 0);
        a1 = __builtin_amdgcn_mfma_f32_16x16x32_bf16(x1, bb, a1, 0, 0, 0);
      }
      if (g == 2){
        if (valid){
          float bias = bv[colc];
          unsigned vb = OFF_VT + (unsigned)(hl*HD + dd)*VTSTR;
          int r0 = rh*32 + lg*4;
          if (r0 < SS){
            *(unsigned*)(sm + vb + (unsigned)r0*2) = packbf(a0[0]+bias, a0[1]+bias);
            if (r0+2 < SS) *(unsigned*)(sm + vb + (unsigned)r0*2 + 4) = packbf(a0[2]+bias, a0[3]+bias);
          }
          int r1 = rh*32 + 16 + lg*4;
          if (r1 < SS){
            *(unsigned*)(sm + vb + (unsigned)r1*2) = packbf(a1[0]+bias, a1[1]+bias);
            if (r1+2 < SS) *(unsigned*)(sm + vb + (unsigned)r1*2 + 4) = packbf(a1[2]+bias, a1[3]+bias);
          }
        }
      } else if (g != 3){
        if (valid){
          float bias = (g==0) ? bq[colc] : bqp[colc];
          unsigned qb = OFF_Q + (unsigned)hl*96 + (unsigned)dd*2 + (g==1 ? 40u : 0u);
          #pragma unroll
          for (int i = 0; i < 4; ++i){
            int r0 = rh*32 + lg*4 + i;
            if (r0 < SS) *(unsigned short*)(sm + qb + (unsigned)r0*QKSTR) = f2bf(a0[i]+bias);
            int r1 = rh*32 + 16 + lg*4 + i;
            if (r1 < SS) *(unsigned short*)(sm + qb + (unsigned)r1*QKSTR) = f2bf(a1[i]+bias);
          }
        }
      } else {
        float bkc = bk[colc];
        if (valid){
          unsigned kb = OFF_K + (unsigned)hl*96 + (unsigned)dd*2 + 40u;
          #pragma unroll
          for (int i = 0; i < 4; ++i){
            int r0 = rh*32 + lg*4 + i;
            if (r0 < SS) *(unsigned short*)(sm + kb + (unsigned)r0*QKSTR) = f2bf(a0[i]+bkc);
            int r1 = rh*32 + 16 + lg*4 + i;
            if (r1 < SS) *(unsigned short*)(sm + kb + (unsigned)r1*QKSTR) = f2bf(a1[i]+bkc);
          }
        }
        const short* wb2 = wkpT + (size_t)col*320 + lg*8;
        #pragma unroll
        for (int st = 0; st < 10; ++st){
          bf8t bb = *(const bf8t*)(wb2 + st*32);
          bf8t x0 = *(const bf8t*)(sm + OFF_UE + (unsigned)(rh*32 + lm)*656u + (unsigned)(st*32 + lg*8)*2u);
          bf8t x1 = *(const bf8t*)(sm + OFF_UE + (unsigned)(rh*32 + 16 + lm)*656u + (unsigned)(st*32 + lg*8)*2u);
          a0 = __builtin_amdgcn_mfma_f32_16x16x32_bf16(x0, bb, a0, 0, 0, 0);
          a1 = __builtin_amdgcn_mfma_f32_16x16x32_bf16(x1, bb, a1, 0, 0, 0);
        }
        if (valid){
          float bsum = bkc + bkp[colc];
          unsigned kb = OFF_K + (unsigned)hl*96 + (unsigned)dd*2;
          #pragma unroll
          for (int i = 0; i < 4; ++i){
            int r0 = rh*32 + lg*4 + i;
            if (r0 < SS) *(unsigned short*)(sm + kb + (unsigned)r0*QKSTR) = f2bf(a0[i]+bsum);
            int r1 = rh*32 + 16 + lg*4 + i;
            if (r1 < SS) *(unsigned short*)(sm + kb + (unsigned)r1*QKSTR) = f2bf(a1[i]+bsum);
          }
        }
      }
    }
    __syncthreads();
    const int ahl = w >> 1, rt = w & 1;
    const bool act = (ahl < nheads);
    f16t s0, s1;
    if (act){
      s0 = zero16(); s1 = zero16();
      unsigned aoff = OFF_Q + (unsigned)(rt*32 + l31)*QKSTR + (unsigned)ahl*96 + (unsigned)hi*16;
      unsigned koff = OFF_K + (unsigned)l31*QKSTR + (unsigned)ahl*96 + (unsigned)hi*16;
      #pragma unroll
      for (int ks = 0; ks < 3; ++ks){
        bf8t a  = *(const bf8t*)(sm + aoff + ks*32);
        bf8t b0 = *(const bf8t*)(sm + koff + ks*32);
        bf8t b1 = *(const bf8t*)(sm + koff + 32u*QKSTR + ks*32);
        s0 = __builtin_amdgcn_mfma_f32_32x32x16_bf16(a, b0, s0, 0, 0, 0);
        s1 = __builtin_amdgcn_mfma_f32_32x32x16_bf16(a, b1, s1, 0, 0, 0);
      }
    }
    __syncthreads();
    if (act){
      const bool m1 = (l31 >= 18);
      unsigned pb = OFF_P + (unsigned)w*PBLK;
      float rinv[16];
      #pragma unroll
      for (int r = 0; r < 16; ++r){
        int lrow = (r&3) + 8*(r>>2) + 4*hi;
        float v0 = s0[r]*rscale;
        float v1 = m1 ? -INFINITY : s1[r]*rscale;
        float mx = fmaxf(v0, v1);
        #pragma unroll
        for (int off = 1; off <= 16; off <<= 1) mx = fmaxf(mx, __shfl_xor(mx, off));
        float e0 = __expf(v0 - mx);
        float e1 = m1 ? 0.f : __expf(v1 - mx);
        float sum = e0 + e1;
        #pragma unroll
        for (int off = 1; off <= 16; off <<= 1) sum += __shfl_xor(sum, off);
        rinv[r] = 1.0f/sum;
        *(unsigned short*)(sm + pb + (unsigned)lrow*PSTR + (unsigned)l31*2)      = f2bf(e0);
        *(unsigned short*)(sm + pb + (unsigned)lrow*PSTR + 64 + (unsigned)l31*2) = f2bf(e1);
      }
      f16t c = zero16();
      unsigned pa  = pb + (unsigned)l31*PSTR + (unsigned)hi*16;
      unsigned vb2 = OFF_VT + (unsigned)(ahl*HD + l31)*VTSTR + (unsigned)hi*16;
      #pragma unroll
      for (int ks = 0; ks < 4; ++ks){
        bf8t a = *(const bf8t*)(sm + pa + ks*32);
        bf8t v = *(const bf8t*)(sm + vb2 + ks*32);
        c = __builtin_amdgcn_mfma_f32_32x32x16_bf16(a, v, c, 0, 0, 0);
      }
      if (l31 < HD){
        int h = nb4*4 + ahl;
        #pragma unroll
        for (int r = 0; r < 16; ++r){
          int q = rt*32 + (r&3) + 8*(r>>2) + 4*hi;
          if (q < SS)
            *(unsigned short*)(sm + OFF_CTX + (unsigned)q*656 + (unsigned)(h*HD + l31)*2) =
                f2bf(c[r]*rinv[r]);
        }
      }
    }
  }
  __syncthreads();

  {
    f4t accp[2][4];
    #pragma unroll
    for (int t = 0; t < 2; ++t)
      #pragma unroll
      for (int r = 0; r < 4; ++r) accp[t][r] = (f4t){0.f,0.f,0.f,0.f};
    gemm10<2,12>(sm, OFF_CTX, waT, lane, w, accp);
    float part[4][4];
    #pragma unroll
    for (int rt2 = 0; rt2 < 4; ++rt2)
      #pragma unroll
      for (int i = 0; i < 4; ++i) part[rt2][i] = 0.f;
    #pragma unroll
    for (int t = 0; t < 2; ++t){
      int ct = w + t*8; if (ct > 12) ct = 12;
      bool valid = (t == 0) || (w < 5);
      int col = ct*16 + lm;
      float bav = (col < QDIM) ? ba[col] : 0.f;
      float qav = (valid && col < QDIM) ? qa[col] : 0.f;
      #pragma unroll
      for (int rt2 = 0; rt2 < 4; ++rt2)
        #pragma unroll
        for (int i = 0; i < 4; ++i)
          part[rt2][i] += tanhf(accp[t][rt2][i] + bav) * qav;
    }
    #pragma unroll
    for (int off = 1; off <= 8; off <<= 1)
      #pragma unroll
      for (int rt2 = 0; rt2 < 4; ++rt2)
        #pragma unroll
        for (int i = 0; i < 4; ++i)
          part[rt2][i] += __shfl_xor(part[rt2][i], off);
    if (lm == 0){
      #pragma unroll
      for (int rt2 = 0; rt2 < 4; ++rt2)
        #pragma unroll
        for (int i = 0; i < 4; ++i){
          int row = rt2*16 + lg*4 + i;
          if (row < SS) *(float*)(sm + OFF_LG + (unsigned)(row*8 + w)*4) = part[rt2][i];
        }
    }
  }
  __syncthreads();
  if (w == 0){
    const int sl = lane < SS ? lane : SS - 1;
    const bool rowok = lane < SS;
    float lgv = -INFINITY;
    if (rowok){
      float s = 0.f;
      #pragma unroll
      for (int j = 0; j < 8; ++j) s += *(const float*)(sm + OFF_LG + (unsigned)(sl*8 + j)*4);
      lgv = s;
    }
    float m = lgv;
    #pragma unroll
    for (int off = 32; off; off >>= 1) m = fmaxf(m, __shfl_xor(m, off));
    float e = rowok ? __expf(lgv - m) : 0.f;
    float ssum = e;
    #pragma unroll
    for (int off = 32; off; off >>= 1) ssum += __shfl_xor(ssum, off);
    *(float*)(sm + OFF_A2 + lane*4) = e / ssum;
  }
  __syncthreads();
  if (tid < DD){
    float accv = 0.f;
    for (int s = 0; s < SS; ++s){
      float av = *(const float*)(sm + OFF_A2 + (unsigned)s*4);
      unsigned short cv = *(const unsigned short*)(sm + OFF_CTX + (unsigned)s*656 + (unsigned)tid*2);
      accv = fmaf(av, __uint_as_float((unsigned)cv << 16), accv);
    }
    out[(size_t)b*DD + tid] = accv;
  }
}

extern "C" void kernel_launch(void* const* d_in, const int* in_sizes, int n_in,
                              void* d_out, int out_size, void* d_ws, size_t ws_size,
                              hipStream_t stream){
  (void)n_in; (void)out_size;
  const int*   ids = (const int*)  d_in[0];
  const float* uvp = (const float*)d_in[1];
  const float* emb = (const float*)d_in[2];
  const float* Wq  = (const float*)d_in[3];
  const float* bq  = (const float*)d_in[4];
  const float* Wk  = (const float*)d_in[5];
  const float* bk  = (const float*)d_in[6];
  const float* Wv  = (const float*)d_in[7];
  const float* bv  = (const float*)d_in[8];
  const float* Wqp = (const float*)d_in[9];
  const float* bqp = (const float*)d_in[10];
  const float* Wkp = (const float*)d_in[11];
  const float* bkp = (const float*)d_in[12];
  const float* Wa  = (const float*)d_in[13];
  const float* ba  = (const float*)d_in[14];
  const float* qa  = (const float*)d_in[15];
  short* wsb = (short*)d_ws;

  const int nb = in_sizes[0] / SS;   // 1024
  const int M  = nb * SS;            // 51200
  const int msuper = (M + 1023) / 1024;

  // ws layout (bf16 elems): weights | a2 [M][320] | 5 x C [M][300]; cg aliases a2
  const size_t AOFF  = WTOT;
  const size_t AELEM = (size_t)M * 320;
  const size_t C0    = AOFF + AELEM;
  const size_t CELEM = (size_t)M * DD;
  const size_t need  = (C0 + 5*CELEM) * 2;

  conv_weights<<<(WTOT + 255)/256, 256, 0, stream>>>(Wq, Wk, Wv, Wqp, Wkp, Wa, wsb);

  if (ws_size >= need){
    short* a2  = wsb + AOFF;
    short* qcg = wsb + C0;
    short* kcg = qcg + CELEM;
    short* vg  = kcg + CELEM;
    short* qpg = vg  + CELEM;
    short* kpg = qpg + CELEM;
    short* cg  = a2;   // alias: a2 dead after k1

    k0_gather<<<nb, 512, 0, stream>>>(ids, emb, a2);
    k1_gemm<<<25*msuper, 512, 0, stream>>>(uvp, (const short*)a2, (const short*)wsb,
                                           bq, bk, bv, bqp, bkp,
                                           qcg, kcg, vg, qpg, kpg, msuper, M);
    k2_attn<<<nb*4, 512, 0, stream>>>((const short*)qcg, (const short*)qpg,
                                      (const short*)kcg, (const short*)kpg,
                                      (const short*)vg, cg);
    k3_pool<<<nb, 512, 0, stream>>>((const short*)cg, (const short*)wsb,
                                    ba, qa, (float*)d_out);
  } else {
    user_enc_kernel<<<nb, 512, 0, stream>>>(ids, uvp, emb,
                                            bq, bk, bv, bqp, bkp, ba, qa,
                                            (const short*)wsb, (float*)d_out);
  }
}

// Round 14
// 476.379 us; speedup vs baseline: 1.7283x; 1.7283x over previous
//
#include <hip/hip_runtime.h>
#include <hip/hip_bf16.h>

#define SS   50     // sequence length
#define DD   300    // embedding dim
#define NH   15     // heads
#define HD   20     // per-head dim
#define QDIM 200    // additive attention dim

// ws (bf16 elements): 5 proj [304][320] + Wa [208][320]
#define WSEG  97280
#define WAOFF 486400
#define WTOT  552960

typedef __attribute__((ext_vector_type(8)))  short bf8t;
typedef __attribute__((ext_vector_type(4)))  float f4t;
typedef __attribute__((ext_vector_type(16))) float f16t;

__device__ __forceinline__ float bflo(unsigned p){ return __uint_as_float(p << 16); }
__device__ __forceinline__ float bfhi(unsigned p){ return __uint_as_float(p & 0xffff0000u); }
__device__ __forceinline__ unsigned short f2bf(float x){
  unsigned u = __float_as_uint(x);
  return (unsigned short)((u + 0x7fffu + ((u >> 16) & 1u)) >> 16);
}
__device__ __forceinline__ unsigned packbf(float a, float b){
  return (unsigned)f2bf(a) | ((unsigned)f2bf(b) << 16);
}
__device__ __forceinline__ f16t zero16(){
  f16t v;
  #pragma unroll
  for (int i = 0; i < 16; ++i) v[i] = 0.f;
  return v;
}

// ---------------- weight converter: f32 [300][N] -> bf16 [Npad][320] (B^T, zero-padded)
__global__ __launch_bounds__(256) void conv_weights(
    const float* __restrict__ Wq, const float* __restrict__ Wk,
    const float* __restrict__ Wv, const float* __restrict__ Wqp,
    const float* __restrict__ Wkp, const float* __restrict__ Wa,
    short* __restrict__ ws)
{
  int idx = blockIdx.x*256 + threadIdx.x;
  if (idx >= WTOT) return;
  float v = 0.f;
  if (idx < WAOFF){
    int seg = idx / WSEG, r = idx - seg*WSEG;
    int n = r / 320, k = r - n*320;
    const float* W = (seg==0)?Wq:(seg==1)?Wk:(seg==2)?Wv:(seg==3)?Wqp:Wkp;
    if (n < DD && k < DD) v = W[k*DD + n];
  } else {
    int r = idx - WAOFF;
    int n = r / 320, k = r - n*320;
    if (n < QDIM && k < DD) v = Wa[k*QDIM + n];
  }
  ws[idx] = (short)f2bf(v);
}

// ============================ K0: ue gather -> bf16 [M][320] =================
__global__ __launch_bounds__(512) void k0_gather(
    const int* __restrict__ ids, const float* __restrict__ emb,
    short* __restrict__ a2)
{
  __shared__ int sid[SS];
  const int tid = threadIdx.x, b = blockIdx.x;
  if (tid < SS) sid[tid] = ids[(size_t)b*SS + tid];
  __syncthreads();
  for (int i = tid; i < SS*160; i += 512){
    int s = i/160, j2 = i - s*160;          // j2-th u32 (2 elems), 160/row
    unsigned v = 0;
    if (j2 < 150){
      float2 t = *(const float2*)(emb + (size_t)sid[s]*DD + j2*2);
      v = packbf(t.x, t.y);
    }
    *(unsigned*)(a2 + ((size_t)b*SS + s)*320 + j2*2) = v;
  }
}

// ============================ K1: tiled GEMM (32x32x16, A in regs) ===========
// 25 slabs x mtiles blocks; round-11 XCD-affine mapping (validated: FETCH 50MB).
// Block: M-tile 128 x N-tile 64. 8 waves = 4M x 2N; wave = 32 rows x 32 cols,
// mfma_f32_32x32x16_bf16, 20 k-steps. A: per-lane global loads (L2 hits) into
// registers, 2 batches of 10 steps (40 VGPR live). B: staged once in LDS
// (stride 656, bank-optimal for 32-lane b128 col reads). ONE barrier total.
// seg 0,1,2: A = uv f32 (convert in-lane); seg 3,4: A = a2 bf16.
#define G_SM  41984

__global__ __launch_bounds__(512, 4) void k1_gemm(
    const float* __restrict__ uv, const short* __restrict__ a2,
    const short* __restrict__ wsb,
    const float* __restrict__ bq, const float* __restrict__ bk,
    const float* __restrict__ bv, const float* __restrict__ bqp,
    const float* __restrict__ bkp,
    short* __restrict__ qc, short* __restrict__ kc, short* __restrict__ vv,
    short* __restrict__ qp, short* __restrict__ kp,
    int mtiles, int M)
{
  __shared__ __align__(16) unsigned char sm[G_SM];
  const int tid  = threadIdx.x;
  const int bid  = blockIdx.x;
  int slab, mt;
  if ((mtiles & 7) == 0){
    int x = bid & 7, j = bid >> 3;
    int q25 = j / 25;
    mt   = x*(mtiles >> 3) + q25;
    slab = j - q25*25;
  } else {
    slab = bid / mtiles; mt = bid - slab*mtiles;
  }
  const int seg  = slab / 5;
  const int col0 = (slab - seg*5)*64;
  const int row0 = mt*128;

  // ---- stage B slab once: 64 cols x 640B = 2560 x 16B chunks, stride 656 ----
  const short* bsrc = wsb + (size_t)seg*WSEG + (size_t)col0*320;
  for (int i = tid; i < 2560; i += 512){
    int c = i/40, k8 = i - c*40;
    *(float4*)(sm + (unsigned)c*656 + (unsigned)k8*16) =
        *(const float4*)(bsrc + (size_t)c*320 + k8*8);
  }
  __syncthreads();                          // B slab visible; the ONLY barrier
  __builtin_amdgcn_sched_barrier(0);        // pin: nothing crosses the barrier

  const int w = tid >> 6, lane = tid & 63;
  const int l31 = lane & 31, hi = lane >> 5;
  const int mw = w & 3, nw2 = w >> 2;
  const bool segA2 = (seg >= 3);

  int rowA = row0 + mw*32 + l31; if (rowA > M-1) rowA = M-1;
  const unsigned bcol = (unsigned)(nw2*32 + l31)*656u + (unsigned)hi*16u;

  f16t acc = zero16();
  #pragma unroll 1
  for (int half = 0; half < 2; ++half){
    // ---- preload 10 k-steps of this lane's A: k = half*160 + st*16 + hi*8 ----
    uint4 a[10];
    if (segA2){
      const short* ap = a2 + (size_t)rowA*320 + half*160 + hi*8;
      #pragma unroll
      for (int st = 0; st < 10; ++st)
        a[st] = *(const uint4*)(ap + st*16);
    } else {
      const float* up = uv + (size_t)rowA*DD;
      #pragma unroll
      for (int st = 0; st < 10; ++st){
        int k0e = half*160 + st*16 + hi*8;
        float v[8];
        if (k0e + 8 <= DD){
          float4 p = *(const float4*)(up + k0e);
          float4 q = *(const float4*)(up + k0e + 4);
          v[0]=p.x; v[1]=p.y; v[2]=p.z; v[3]=p.w;
          v[4]=q.x; v[5]=q.y; v[6]=q.z; v[7]=q.w;
        } else {
          #pragma unroll
          for (int j = 0; j < 8; ++j){
            int kk = k0e + j;
            v[j] = (kk < DD) ? up[kk] : 0.f;
          }
        }
        a[st] = (uint4){ packbf(v[0],v[1]), packbf(v[2],v[3]),
                         packbf(v[4],v[5]), packbf(v[6],v[7]) };
      }
    }
    // ---- 10 x {1 b128 B-read, 1 MFMA 32x32x16} (B read-only; no barriers) ----
    #pragma unroll
    for (int st = 0; st < 10; ++st){
      bf8t bfrag = *(const bf8t*)(sm + bcol + (unsigned)(half*320 + st*32));
      acc = __builtin_amdgcn_mfma_f32_32x32x16_bf16(*(const bf8t*)&a[st], bfrag, acc, 0, 0, 0);
    }
  }

  // ---- epilogue: bias + bf16 store to natural [M][300] ----
  const float* bias = (seg==0)?bq:(seg==1)?bk:(seg==2)?bv:(seg==3)?bqp:bkp;
  short* outp = (seg==0)?qc:(seg==1)?kc:(seg==2)?vv:(seg==3)?qp:kp;
  const int colseg = col0 + nw2*32 + l31;
  if (colseg < DD){
    float bb = bias[colseg];
    #pragma unroll
    for (int r = 0; r < 16; ++r){
      int row = row0 + mw*32 + (r&3) + 8*(r>>2) + 4*hi;
      if (row < M) outp[(size_t)row*DD + colseg] = (short)f2bf(acc[r] + bb);
    }
  }
}

// ============================ K2: attention ==================================
// block = (b, head-group hg of <=4 heads). LDS:
//   Q [50][192]bf16 stride400 @0 ([Qc20|Qp20|8z] per head)
//   K @20000 ([Ksum20|Kc20|8z], Ksum = Kc+Kp)
//   VT [92][64keys]bf16 stride144 @40000 ; P overlays Q/K: per-wave [32][64] @ w*4608
#define A_Q   0
#define A_K   20000
#define A_VT  40000
#define A_PBLK 4608
#define A_SM  53248

__global__ __launch_bounds__(512) void k2_attn(
    const short* __restrict__ qcg, const short* __restrict__ qpg,
    const short* __restrict__ kcg, const short* __restrict__ kpg,
    const short* __restrict__ vg,  short* __restrict__ cg)
{
  __shared__ __align__(16) unsigned char sm[A_SM];
  const int tid  = threadIdx.x;
  const int bid  = blockIdx.x;
  const int b    = bid >> 2;
  const int hg   = bid & 3;
  const int nheads = (hg < 3) ? 4 : 3;
  const int w    = tid >> 6;
  const int lane = tid & 63;
  const int l31  = lane & 31, hi = lane >> 5;

  // zero VT (keys>=50 must be 0; rows 80..91 finite)
  for (int i = tid; i < 828; i += 512)
    *(float4*)(sm + A_VT + (unsigned)i*16) = make_float4(0.f,0.f,0.f,0.f);
  __syncthreads();
  // stage Q: per (row,hl): [Qc20|Qp20|pad8] (src col clamped for head 15)
  for (int i = tid; i < 4800; i += 512){
    int rhd = i / 24, j = i - rhd*24;
    int row = rhd >> 2, hl = rhd & 3;
    int hc = (hg*4 + hl)*20; if (hc > 280) hc = 280;
    const size_t rbase = ((size_t)b*SS + row)*(size_t)DD + hc;
    unsigned char* ldst = sm + A_Q + (unsigned)row*400 + (unsigned)hl*96;
    if (j < 10)      *(unsigned*)(ldst + j*4)           = *(const unsigned*)(qcg + rbase + j*2);
    else if (j < 20) *(unsigned*)(ldst + 40 + (j-10)*4) = *(const unsigned*)(qpg + rbase + (j-10)*2);
    else             *(unsigned*)(ldst + 80 + (j-20)*4) = 0u;
  }
  // stage K: [Ksum20|Kc20|pad8]
  for (int i = tid; i < 4800; i += 512){
    int rhd = i / 24, j = i - rhd*24;
    int row = rhd >> 2, hl = rhd & 3;
    int hc = (hg*4 + hl)*20; if (hc > 280) hc = 280;
    const size_t rbase = ((size_t)b*SS + row)*(size_t)DD + hc;
    unsigned char* ldst = sm + A_K + (unsigned)row*400 + (unsigned)hl*96;
    if (j < 10){
      unsigned c = *(const unsigned*)(kcg + rbase + j*2);
      unsigned p = *(const unsigned*)(kpg + rbase + j*2);
      *(unsigned*)(ldst + j*4) = packbf(bflo(c)+bflo(p), bfhi(c)+bfhi(p));
    } else if (j < 20){
      *(unsigned*)(ldst + 40 + (j-10)*4) = *(const unsigned*)(kcg + rbase + (j-10)*2);
    } else {
      *(unsigned*)(ldst + 80 + (j-20)*4) = 0u;
    }
  }
  // stage VT (transpose): u32 (2 dims) per (row,d2); src col clamped
  for (int i = tid; i < 2000; i += 512){
    int row = i/40, d2 = i - row*40;
    int col = hg*80 + d2*2; if (col > 298) col = 298;
    unsigned v = *(const unsigned*)(vg + ((size_t)b*SS + row)*(size_t)DD + col);
    *(unsigned short*)(sm + A_VT + (unsigned)(d2*2)*144   + (unsigned)row*2) = (unsigned short)(v & 0xffffu);
    *(unsigned short*)(sm + A_VT + (unsigned)(d2*2+1)*144 + (unsigned)row*2) = (unsigned short)(v >> 16);
  }
  __syncthreads();

  const float rscale = 0.1290994449f;  // 1/sqrt(3*DK)
  const int ahl = w >> 1, rt = w & 1;
  const bool act = (ahl < nheads);
  f16t s0, s1;
  if (act){
    s0 = zero16(); s1 = zero16();
    unsigned aoff = A_Q + (unsigned)(rt*32 + l31)*400 + (unsigned)ahl*96 + (unsigned)hi*16;
    unsigned koff = A_K + (unsigned)l31*400 + (unsigned)ahl*96 + (unsigned)hi*16;
    #pragma unroll
    for (int ks = 0; ks < 3; ++ks){
      bf8t a  = *(const bf8t*)(sm + aoff + ks*32);
      bf8t b0 = *(const bf8t*)(sm + koff + ks*32);
      bf8t b1 = *(const bf8t*)(sm + koff + 32u*400 + ks*32);
      s0 = __builtin_amdgcn_mfma_f32_32x32x16_bf16(a, b0, s0, 0, 0, 0);
      s1 = __builtin_amdgcn_mfma_f32_32x32x16_bf16(a, b1, s1, 0, 0, 0);
    }
  }
  __syncthreads();   // Q/K reads done -> P may overwrite
  if (act){
    const bool m1 = (l31 >= 18);   // key 32+l31 >= 50
    unsigned pb = (unsigned)w*A_PBLK;
    float rinv[16];
    #pragma unroll
    for (int r = 0; r < 16; ++r){
      int lrow = (r&3) + 8*(r>>2) + 4*hi;
      float v0 = s0[r]*rscale;
      float v1 = m1 ? -INFINITY : s1[r]*rscale;
      float mx = fmaxf(v0, v1);
      #pragma unroll
      for (int off = 1; off <= 16; off <<= 1) mx = fmaxf(mx, __shfl_xor(mx, off));
      float e0 = __expf(v0 - mx);
      float e1 = m1 ? 0.f : __expf(v1 - mx);
      float sum = e0 + e1;
      #pragma unroll
      for (int off = 1; off <= 16; off <<= 1) sum += __shfl_xor(sum, off);
      rinv[r] = 1.0f/sum;
      *(unsigned short*)(sm + pb + (unsigned)lrow*144 + (unsigned)l31*2)      = f2bf(e0);
      *(unsigned short*)(sm + pb + (unsigned)lrow*144 + 64 + (unsigned)l31*2) = f2bf(e1);
    }
    f16t c = zero16();
    unsigned pa  = pb + (unsigned)l31*144 + (unsigned)hi*16;
    unsigned vb2 = A_VT + (unsigned)(ahl*HD + l31)*144 + (unsigned)hi*16;
    #pragma unroll
    for (int ks = 0; ks < 4; ++ks){
      bf8t a = *(const bf8t*)(sm + pa + ks*32);
      bf8t v = *(const bf8t*)(sm + vb2 + ks*32);
      c = __builtin_amdgcn_mfma_f32_32x32x16_bf16(a, v, c, 0, 0, 0);
    }
    if (l31 < HD){
      int h = hg*4 + ahl;
      #pragma unroll
      for (int r = 0; r < 16; ++r){
        int q = rt*32 + (r&3) + 8*(r>>2) + 4*hi;
        if (q < SS)
          cg[((size_t)b*SS + q)*DD + h*HD + l31] = (short)f2bf(c[r]*rinv[r]);
      }
    }
  }
}

// ============================ K3: pooling ====================================
#define B_CTX 0
#define B_LG  41984
#define B_A2  44032
#define B_SM  44288

template<int NT, int NCTM>
__device__ __forceinline__ void gemm10(const unsigned char* sm, unsigned abase,
                                       const short* __restrict__ wt,
                                       int lane, int w, f4t (&acc)[NT][4])
{
  const int lm = lane & 15, lg = lane >> 4;
  #pragma unroll
  for (int step = 0; step < 10; ++step){
    bf8t a[4];
    #pragma unroll
    for (int rt = 0; rt < 4; ++rt)
      a[rt] = *(const bf8t*)(sm + abase + (unsigned)(rt*16 + lm)*656u + (unsigned)(step*32 + lg*8)*2u);
    #pragma unroll
    for (int t = 0; t < NT; ++t){
      int ct = w + t*8; if (ct > NCTM) ct = NCTM;
      bf8t bb = *(const bf8t*)(wt + (size_t)(ct*16 + lm)*320 + step*32 + lg*8);
      #pragma unroll
      for (int rt = 0; rt < 4; ++rt)
        acc[t][rt] = __builtin_amdgcn_mfma_f32_16x16x32_bf16(a[rt], bb, acc[t][rt], 0, 0, 0);
    }
  }
}

__global__ __launch_bounds__(512) void k3_pool(
    const short* __restrict__ cg, const short* __restrict__ wsb,
    const float* __restrict__ ba, const float* __restrict__ qa,
    float* __restrict__ out)
{
  __shared__ __align__(16) unsigned char sm[B_SM];
  const int tid  = threadIdx.x;
  const int b    = blockIdx.x;
  const int w    = tid >> 6;
  const int lane = tid & 63;
  const int lm   = lane & 15, lg = lane >> 4;
  const short* waT = wsb + WAOFF;

  for (int i = tid; i < SS*75; i += 512){
    int row = i/75, c = i - row*75;
    uint2 v = *(const uint2*)(cg + ((size_t)b*SS + row)*DD + c*4);
    *(uint2*)(sm + B_CTX + (unsigned)row*656 + (unsigned)c*8) = v;
  }
  for (int i = tid; i < SS*14; i += 512)
    *(unsigned*)(sm + B_CTX + (unsigned)(i/14)*656 + 600u + (unsigned)(i%14)*4) = 0;
  __syncthreads();

  {
    f4t accp[2][4];
    #pragma unroll
    for (int t = 0; t < 2; ++t)
      #pragma unroll
      for (int r = 0; r < 4; ++r) accp[t][r] = (f4t){0.f,0.f,0.f,0.f};
    gemm10<2,12>(sm, B_CTX, waT, lane, w, accp);
    float part[4][4];
    #pragma unroll
    for (int rt2 = 0; rt2 < 4; ++rt2)
      #pragma unroll
      for (int i = 0; i < 4; ++i) part[rt2][i] = 0.f;
    #pragma unroll
    for (int t = 0; t < 2; ++t){
      int ct = w + t*8; if (ct > 12) ct = 12;
      bool valid = (t == 0) || (w < 5);
      int col = ct*16 + lm;
      float bav = (col < QDIM) ? ba[col] : 0.f;
      float qav = (valid && col < QDIM) ? qa[col] : 0.f;
      #pragma unroll
      for (int rt2 = 0; rt2 < 4; ++rt2)
        #pragma unroll
        for (int i = 0; i < 4; ++i)
          part[rt2][i] += tanhf(accp[t][rt2][i] + bav) * qav;
    }
    #pragma unroll
    for (int off = 1; off <= 8; off <<= 1)
      #pragma unroll
      for (int rt2 = 0; rt2 < 4; ++rt2)
        #pragma unroll
        for (int i = 0; i < 4; ++i)
          part[rt2][i] += __shfl_xor(part[rt2][i], off);
    if (lm == 0){
      #pragma unroll
      for (int rt2 = 0; rt2 < 4; ++rt2)
        #pragma unroll
        for (int i = 0; i < 4; ++i){
          int row = rt2*16 + lg*4 + i;
          if (row < SS) *(float*)(sm + B_LG + (unsigned)(row*8 + w)*4) = part[rt2][i];
        }
    }
  }
  __syncthreads();
  if (w == 0){
    const int sl = lane < SS ? lane : SS - 1;
    const bool rowok = lane < SS;
    float lgv = -INFINITY;
    if (rowok){
      float s = 0.f;
      #pragma unroll
      for (int j = 0; j < 8; ++j) s += *(const float*)(sm + B_LG + (unsigned)(sl*8 + j)*4);
      lgv = s;
    }
    float m = lgv;
    #pragma unroll
    for (int off = 32; off; off >>= 1) m = fmaxf(m, __shfl_xor(m, off));
    float e = rowok ? __expf(lgv - m) : 0.f;
    float ssum = e;
    #pragma unroll
    for (int off = 32; off; off >>= 1) ssum += __shfl_xor(ssum, off);
    *(float*)(sm + B_A2 + lane*4) = e / ssum;
  }
  __syncthreads();
  if (tid < DD){
    float accv = 0.f;
    for (int s = 0; s < SS; ++s){
      float av = *(const float*)(sm + B_A2 + (unsigned)s*4);
      unsigned short cv = *(const unsigned short*)(sm + B_CTX + (unsigned)s*656 + (unsigned)tid*2);
      accv = fmaf(av, __uint_as_float((unsigned)cv << 16), accv);
    }
    out[(size_t)b*DD + tid] = accv;
  }
}

// ===================== fallback: round-4 fused kernel ========================
#define OFF_UV  0
#define OFF_UE  32800
#define QKSTR   400
#define OFF_Q   65600
#define OFF_K   85600
#define OFF_P   65600
#define PBLK    4608
#define PSTR    144
#define VTSTR   144
#define OFF_VT  105600
#define OFF_CTX 117120
#define OFF_LG  159104
#define OFF_A2  161152
#define OFF_IDS 161408
#define SM_TOTAL 161616

__global__ __launch_bounds__(512) void user_enc_kernel(
    const int*   __restrict__ ids, const float* __restrict__ uv,
    const float* __restrict__ emb,
    const float* __restrict__ bq, const float* __restrict__ bk,
    const float* __restrict__ bv, const float* __restrict__ bqp,
    const float* __restrict__ bkp,
    const float* __restrict__ ba, const float* __restrict__ qa,
    const short* __restrict__ wsb, float* __restrict__ out)
{
  __shared__ __align__(16) unsigned char sm[SM_TOTAL];
  const int tid  = threadIdx.x;
  const int b    = blockIdx.x;
  const int w    = tid >> 6;
  const int lane = tid & 63;
  const int lm   = lane & 15, lg = lane >> 4;
  const int l31  = lane & 31, hi = lane >> 5;

  const short* wqT  = wsb;
  const short* wkT  = wsb + WSEG;
  const short* wvT  = wsb + 2*WSEG;
  const short* wqpT = wsb + 3*WSEG;
  const short* wkpT = wsb + 4*WSEG;
  const short* waT  = wsb + WAOFF;

  if (tid < SS) *(int*)(sm + OFF_IDS + tid*4) = ids[(size_t)b*SS + tid];
  {
    const float* srcv = uv + (size_t)b*SS*DD;
    for (int i = tid; i < SS*75; i += 512){
      int s = i/75, j4 = i - s*75;
      float4 v = *(const float4*)(srcv + s*DD + j4*4);
      *(unsigned*)(sm + OFF_UV + (unsigned)s*656 + (unsigned)j4*8)     = packbf(v.x, v.y);
      *(unsigned*)(sm + OFF_UV + (unsigned)s*656 + (unsigned)j4*8 + 4) = packbf(v.z, v.w);
    }
    for (int i = tid; i < SS*28; i += 512){
      int s = i/28, j = i - s*28;
      unsigned off = (j < 14) ? (OFF_UV + (unsigned)s*656 + 600u + (unsigned)j*4)
                              : (OFF_UE + (unsigned)s*656 + 600u + (unsigned)(j-14)*4);
      *(unsigned*)(sm + off) = 0;
    }
    for (int i = tid; i < SS*14; i += 512)
      *(unsigned*)(sm + OFF_CTX + (unsigned)(i/14)*656 + 600u + (unsigned)(i%14)*4) = 0;
    for (int i = tid; i < 720; i += 512)
      *(float4*)(sm + OFF_VT + (unsigned)i*16) = make_float4(0.f,0.f,0.f,0.f);
  }
  __syncthreads();
  for (int i = tid; i < SS*75; i += 512){
    int s = i/75, j4 = i - s*75;
    int id = *(const int*)(sm + OFF_IDS + s*4);
    float4 v = *(const float4*)(emb + (size_t)id*DD + j4*4);
    *(unsigned*)(sm + OFF_UE + (unsigned)s*656 + (unsigned)j4*8)     = packbf(v.x, v.y);
    *(unsigned*)(sm + OFF_UE + (unsigned)s*656 + (unsigned)j4*8 + 4) = packbf(v.z, v.w);
  }

  const float rscale = 0.1290994449f;
  #pragma unroll 1
  for (int nb4 = 0; nb4 < 4; ++nb4){
    const int nheads = (nb4 < 3) ? 4 : 3;
    const int NCT    = (nb4 < 3) ? 5 : 4;
    __syncthreads();
    for (int i = tid; i < SS*4; i += 512){
      int r = i >> 2, hl0 = i & 3;
      *(float4*)(sm + OFF_Q + (unsigned)r*QKSTR + (unsigned)hl0*96 + 80) = make_float4(0.f,0.f,0.f,0.f);
      *(float4*)(sm + OFF_K + (unsigned)r*QKSTR + (unsigned)hl0*96 + 80) = make_float4(0.f,0.f,0.f,0.f);
    }
    for (int ht = w; ht < 8*NCT; ht += 8){
      const int g   = (ht >= 6*NCT) ? 3 : (ht >= 4*NCT) ? 2 : (ht >= 2*NCT) ? 1 : 0;
      const int rem = ht - g*2*NCT;
      const int c   = rem >> 1, rh = rem & 1;
      const int col = nb4*80 + c*16 + lm;
      const int colc = (col < DD) ? col : DD-1;
      const int head = col / HD;
      const int dd   = col - head*HD;
      const int hl   = head - nb4*4;
      const bool valid = (hl < nheads) && (col < DD);
      const unsigned abase = (g == 1) ? (unsigned)OFF_UE : (unsigned)OFF_UV;
      const short* wt = (g==0) ? wqT : (g==1) ? wqpT : (g==2) ? wvT : wkT;
      const short* wb = wt + (size_t)col*320 + lg*8;
      f4t a0 = {0.f,0.f,0.f,0.f}, a1 = {0.f,0.f,0.f,0.f};
      #pragma unroll
      for (int st = 0; st < 10; ++st){
        bf8t bb = *(const bf8t*)(wb + st*32);
        bf8t x0 = *(const bf8t*)(sm + abase + (unsigned)(rh*32 + lm)*656u + (unsigned)(st*32 + lg*8)*2u);
        bf8t x1 = *(const bf8t*)(sm + abase + (unsigned)(rh*32 + 16 + lm)*656u + (unsigned)(st*32 + lg*8)*2u);
        a0 = __builtin_amdgcn_mfma_f32_16x16x32_bf16(x0, bb, a0, 0, 0, 0);
        a1 = __builtin_amdgcn_mfma_f32_16x16x32_bf16(x1, bb, a1, 0, 0, 0);
      }
      if (g == 2){
        if (valid){
          float bias = bv[colc];
          unsigned vb = OFF_VT + (unsigned)(hl*HD + dd)*VTSTR;
          int r0 = rh*32 + lg*4;
          if (r0 < SS){
            *(unsigned*)(sm + vb + (unsigned)r0*2) = packbf(a0[0]+bias, a0[1]+bias);
            if (r0+2 < SS) *(unsigned*)(sm + vb + (unsigned)r0*2 + 4) = packbf(a0[2]+bias, a0[3]+bias);
          }
          int r1 = rh*32 + 16 + lg*4;
          if (r1 < SS){
            *(unsigned*)(sm + vb + (unsigned)r1*2) = packbf(a1[0]+bias, a1[1]+bias);
            if (r1+2 < SS) *(unsigned*)(sm + vb + (unsigned)r1*2 + 4) = packbf(a1[2]+bias, a1[3]+bias);
          }
        }
      } else if (g != 3){
        if (valid){
          float bias = (g==0) ? bq[colc] : bqp[colc];
          unsigned qb = OFF_Q + (unsigned)hl*96 + (unsigned)dd*2 + (g==1 ? 40u : 0u);
          #pragma unroll
          for (int i = 0; i < 4; ++i){
            int r0 = rh*32 + lg*4 + i;
            if (r0 < SS) *(unsigned short*)(sm + qb + (unsigned)r0*QKSTR) = f2bf(a0[i]+bias);
            int r1 = rh*32 + 16 + lg*4 + i;
            if (r1 < SS) *(unsigned short*)(sm + qb + (unsigned)r1*QKSTR) = f2bf(a1[i]+bias);
          }
        }
      } else {
        float bkc = bk[colc];
        if (valid){
          unsigned kb = OFF_K + (unsigned)hl*96 + (unsigned)dd*2 + 40u;
          #pragma unroll
          for (int i = 0; i < 4; ++i){
            int r0 = rh*32 + lg*4 + i;
            if (r0 < SS) *(unsigned short*)(sm + kb + (unsigned)r0*QKSTR) = f2bf(a0[i]+bkc);
            int r1 = rh*32 + 16 + lg*4 + i;
            if (r1 < SS) *(unsigned short*)(sm + kb + (unsigned)r1*QKSTR) = f2bf(a1[i]+bkc);
          }
        }
        const short* wb2 = wkpT + (size_t)col*320 + lg*8;
        #pragma unroll
        for (int st = 0; st < 10; ++st){
          bf8t bb = *(const bf8t*)(wb2 + st*32);
          bf8t x0 = *(const bf8t*)(sm + OFF_UE + (unsigned)(rh*32 + lm)*656u + (unsigned)(st*32 + lg*8)*2u);
          bf8t x1 = *(const bf8t*)(sm + OFF_UE + (unsigned)(rh*32 + 16 + lm)*656u + (unsigned)(st*32 + lg*8)*2u);
          a0 = __builtin_amdgcn_mfma_f32_16x16x32_bf16(x0, bb, a0, 0, 0, 0);
          a1 = __builtin_amdgcn_mfma_f32_16x16x32_bf16(x1, bb, a1, 0, 0, 0);
        }
        if (valid){
          float bsum = bkc + bkp[colc];
          unsigned kb = OFF_K + (unsigned)hl*96 + (unsigned)dd*2;
          #pragma unroll
          for (int i = 0; i < 4; ++i){
            int r0 = rh*32 + lg*4 + i;
            if (r0 < SS) *(unsigned short*)(sm + kb + (unsigned)r0*QKSTR) = f2bf(a0[i]+bsum);
            int r1 = rh*32 + 16 + lg*4 + i;
            if (r1 < SS) *(unsigned short*)(sm + kb + (unsigned)r1*QKSTR) = f2bf(a1[i]+bsum);
          }
        }
      }
    }
    __syncthreads();
    const int ahl = w >> 1, rt = w & 1;
    const bool act = (ahl < nheads);
    f16t s0, s1;
    if (act){
      s0 = zero16(); s1 = zero16();
      unsigned aoff = OFF_Q + (unsigned)(rt*32 + l31)*QKSTR + (unsigned)ahl*96 + (unsigned)hi*16;
      unsigned koff = OFF_K + (unsigned)l31*QKSTR + (unsigned)ahl*96 + (unsigned)hi*16;
      #pragma unroll
      for (int ks = 0; ks < 3; ++ks){
        bf8t a  = *(const bf8t*)(sm + aoff + ks*32);
        bf8t b0 = *(const bf8t*)(sm + koff + ks*32);
        bf8t b1 = *(const bf8t*)(sm + koff + 32u*QKSTR + ks*32);
        s0 = __builtin_amdgcn_mfma_f32_32x32x16_bf16(a, b0, s0, 0, 0, 0);
        s1 = __builtin_amdgcn_mfma_f32_32x32x16_bf16(a, b1, s1, 0, 0, 0);
      }
    }
    __syncthreads();
    if (act){
      const bool m1 = (l31 >= 18);
      unsigned pb = OFF_P + (unsigned)w*PBLK;
      float rinv[16];
      #pragma unroll
      for (int r = 0; r < 16; ++r){
        int lrow = (r&3) + 8*(r>>2) + 4*hi;
        float v0 = s0[r]*rscale;
        float v1 = m1 ? -INFINITY : s1[r]*rscale;
        float mx = fmaxf(v0, v1);
        #pragma unroll
        for (int off = 1; off <= 16; off <<= 1) mx = fmaxf(mx, __shfl_xor(mx, off));
        float e0 = __expf(v0 - mx);
        float e1 = m1 ? 0.f : __expf(v1 - mx);
        float sum = e0 + e1;
        #pragma unroll
        for (int off = 1; off <= 16; off <<= 1) sum += __shfl_xor(sum, off);
        rinv[r] = 1.0f/sum;
        *(unsigned short*)(sm + pb + (unsigned)lrow*PSTR + (unsigned)l31*2)      = f2bf(e0);
        *(unsigned short*)(sm + pb + (unsigned)lrow*PSTR + 64 + (unsigned)l31*2) = f2bf(e1);
      }
      f16t c = zero16();
      unsigned pa  = pb + (unsigned)l31*PSTR + (unsigned)hi*16;
      unsigned vb2 = OFF_VT + (unsigned)(ahl*HD + l31)*VTSTR + (unsigned)hi*16;
      #pragma unroll
      for (int ks = 0; ks < 4; ++ks){
        bf8t a = *(const bf8t*)(sm + pa + ks*32);
        bf8t v = *(const bf8t*)(sm + vb2 + ks*32);
        c = __builtin_amdgcn_mfma_f32_32x32x16_bf16(a, v, c, 0, 0, 0);
      }
      if (l31 < HD){
        int h = nb4*4 + ahl;
        #pragma unroll
        for (int r = 0; r < 16; ++r){
          int q = rt*32 + (r&3) + 8*(r>>2) + 4*hi;
          if (q < SS)
            *(unsigned short*)(sm + OFF_CTX + (unsigned)q*656 + (unsigned)(h*HD + l31)*2) =
                f2bf(c[r]*rinv[r]);
        }
      }
    }
  }
  __syncthreads();

  {
    f4t accp[2][4];
    #pragma unroll
    for (int t = 0; t < 2; ++t)
      #pragma unroll
      for (int r = 0; r < 4; ++r) accp[t][r] = (f4t){0.f,0.f,0.f,0.f};
    gemm10<2,12>(sm, OFF_CTX, waT, lane, w, accp);
    float part[4][4];
    #pragma unroll
    for (int rt2 = 0; rt2 < 4; ++rt2)
      #pragma unroll
      for (int i = 0; i < 4; ++i) part[rt2][i] = 0.f;
    #pragma unroll
    for (int t = 0; t < 2; ++t){
      int ct = w + t*8; if (ct > 12) ct = 12;
      bool valid = (t == 0) || (w < 5);
      int col = ct*16 + lm;
      float bav = (col < QDIM) ? ba[col] : 0.f;
      float qav = (valid && col < QDIM) ? qa[col] : 0.f;
      #pragma unroll
      for (int rt2 = 0; rt2 < 4; ++rt2)
        #pragma unroll
        for (int i = 0; i < 4; ++i)
          part[rt2][i] += tanhf(accp[t][rt2][i] + bav) * qav;
    }
    #pragma unroll
    for (int off = 1; off <= 8; off <<= 1)
      #pragma unroll
      for (int rt2 = 0; rt2 < 4; ++rt2)
        #pragma unroll
        for (int i = 0; i < 4; ++i)
          part[rt2][i] += __shfl_xor(part[rt2][i], off);
    if (lm == 0){
      #pragma unroll
      for (int rt2 = 0; rt2 < 4; ++rt2)
        #pragma unroll
        for (int i = 0; i < 4; ++i){
          int row = rt2*16 + lg*4 + i;
          if (row < SS) *(float*)(sm + OFF_LG + (unsigned)(row*8 + w)*4) = part[rt2][i];
        }
    }
  }
  __syncthreads();
  if (w == 0){
    const int sl = lane < SS ? lane : SS - 1;
    const bool rowok = lane < SS;
    float lgv = -INFINITY;
    if (rowok){
      float s = 0.f;
      #pragma unroll
      for (int j = 0; j < 8; ++j) s += *(const float*)(sm + OFF_LG + (unsigned)(sl*8 + j)*4);
      lgv = s;
    }
    float m = lgv;
    #pragma unroll
    for (int off = 32; off; off >>= 1) m = fmaxf(m, __shfl_xor(m, off));
    float e = rowok ? __expf(lgv - m) : 0.f;
    float ssum = e;
    #pragma unroll
    for (int off = 32; off; off >>= 1) ssum += __shfl_xor(ssum, off);
    *(float*)(sm + OFF_A2 + lane*4) = e / ssum;
  }
  __syncthreads();
  if (tid < DD){
    float accv = 0.f;
    for (int s = 0; s < SS; ++s){
      float av = *(const float*)(sm + OFF_A2 + (unsigned)s*4);
      unsigned short cv = *(const unsigned short*)(sm + OFF_CTX + (unsigned)s*656 + (unsigned)tid*2);
      accv = fmaf(av, __uint_as_float((unsigned)cv << 16), accv);
    }
    out[(size_t)b*DD + tid] = accv;
  }
}

extern "C" void kernel_launch(void* const* d_in, const int* in_sizes, int n_in,
                              void* d_out, int out_size, void* d_ws, size_t ws_size,
                              hipStream_t stream){
  (void)n_in; (void)out_size;
  const int*   ids = (const int*)  d_in[0];
  const float* uvp = (const float*)d_in[1];
  const float* emb = (const float*)d_in[2];
  const float* Wq  = (const float*)d_in[3];
  const float* bq  = (const float*)d_in[4];
  const float* Wk  = (const float*)d_in[5];
  const float* bk  = (const float*)d_in[6];
  const float* Wv  = (const float*)d_in[7];
  const float* bv  = (const float*)d_in[8];
  const float* Wqp = (const float*)d_in[9];
  const float* bqp = (const float*)d_in[10];
  const float* Wkp = (const float*)d_in[11];
  const float* bkp = (const float*)d_in[12];
  const float* Wa  = (const float*)d_in[13];
  const float* ba  = (const float*)d_in[14];
  const float* qa  = (const float*)d_in[15];
  short* wsb = (short*)d_ws;

  const int nb = in_sizes[0] / SS;   // 1024
  const int M  = nb * SS;            // 51200
  const int mtiles = (M + 127) / 128;

  // ws layout (bf16 elems): weights | a2 [M][320] | 5 x C [M][300]; cg aliases a2
  const size_t AOFF  = WTOT;
  const size_t AELEM = (size_t)M * 320;
  const size_t C0    = AOFF + AELEM;
  const size_t CELEM = (size_t)M * DD;
  const size_t need  = (C0 + 5*CELEM) * 2;

  conv_weights<<<(WTOT + 255)/256, 256, 0, stream>>>(Wq, Wk, Wv, Wqp, Wkp, Wa, wsb);

  if (ws_size >= need){
    short* a2  = wsb + AOFF;
    short* qcg = wsb + C0;
    short* kcg = qcg + CELEM;
    short* vg  = kcg + CELEM;
    short* qpg = vg  + CELEM;
    short* kpg = qpg + CELEM;
    short* cg  = a2;   // alias: a2 dead after k1

    k0_gather<<<nb, 512, 0, stream>>>(ids, emb, a2);
    k1_gemm<<<25*mtiles, 512, 0, stream>>>(uvp, (const short*)a2, (const short*)wsb,
                                           bq, bk, bv, bqp, bkp,
                                           qcg, kcg, vg, qpg, kpg, mtiles, M);
    k2_attn<<<nb*4, 512, 0, stream>>>((const short*)qcg, (const short*)qpg,
                                      (const short*)kcg, (const short*)kpg,
                                      (const short*)vg, cg);
    k3_pool<<<nb, 512, 0, stream>>>((const short*)cg, (const short*)wsb,
                                    ba, qa, (float*)d_out);
  } else {
    user_enc_kernel<<<nb, 512, 0, stream>>>(ids, uvp, emb,
                                            bq, bk, bv, bqp, bkp, ba, qa,
                                            (const short*)wsb, (float*)d_out);
  }
}

// Round 15
// 434.096 us; speedup vs baseline: 1.8967x; 1.0974x over previous
//
#include <hip/hip_runtime.h>
#include <hip/hip_bf16.h>

#define SS   50     // sequence length
#define DD   300    // embedding dim
#define NH   15     // heads
#define HD   20     // per-head dim
#define QDIM 200    // additive attention dim

// ws (bf16 elements): 5 proj [304][320] + Wa [208][320]
#define WSEG  97280
#define WAOFF 486400
#define WTOT  552960

typedef __attribute__((ext_vector_type(8)))  short bf8t;
typedef __attribute__((ext_vector_type(4)))  float f4t;
typedef __attribute__((ext_vector_type(16))) float f16t;

__device__ __forceinline__ float bflo(unsigned p){ return __uint_as_float(p << 16); }
__device__ __forceinline__ float bfhi(unsigned p){ return __uint_as_float(p & 0xffff0000u); }
__device__ __forceinline__ unsigned short f2bf(float x){
  unsigned u = __float_as_uint(x);
  return (unsigned short)((u + 0x7fffu + ((u >> 16) & 1u)) >> 16);
}
__device__ __forceinline__ unsigned packbf(float a, float b){
  return (unsigned)f2bf(a) | ((unsigned)f2bf(b) << 16);
}
__device__ __forceinline__ f16t zero16(){
  f16t v;
  #pragma unroll
  for (int i = 0; i < 16; ++i) v[i] = 0.f;
  return v;
}

// ---------------- weight converter: f32 [300][N] -> bf16 [Npad][320] (B^T, zero-padded)
__global__ __launch_bounds__(256) void conv_weights(
    const float* __restrict__ Wq, const float* __restrict__ Wk,
    const float* __restrict__ Wv, const float* __restrict__ Wqp,
    const float* __restrict__ Wkp, const float* __restrict__ Wa,
    short* __restrict__ ws)
{
  int idx = blockIdx.x*256 + threadIdx.x;
  if (idx >= WTOT) return;
  float v = 0.f;
  if (idx < WAOFF){
    int seg = idx / WSEG, r = idx - seg*WSEG;
    int n = r / 320, k = r - n*320;
    const float* W = (seg==0)?Wq:(seg==1)?Wk:(seg==2)?Wv:(seg==3)?Wqp:Wkp;
    if (n < DD && k < DD) v = W[k*DD + n];
  } else {
    int r = idx - WAOFF;
    int n = r / 320, k = r - n*320;
    if (n < QDIM && k < DD) v = Wa[k*QDIM + n];
  }
  ws[idx] = (short)f2bf(v);
}

// ============================ K0: ue gather -> bf16 [M][320] =================
__global__ __launch_bounds__(512) void k0_gather(
    const int* __restrict__ ids, const float* __restrict__ emb,
    short* __restrict__ a2)
{
  __shared__ int sid[SS];
  const int tid = threadIdx.x, b = blockIdx.x;
  if (tid < SS) sid[tid] = ids[(size_t)b*SS + tid];
  __syncthreads();
  for (int i = tid; i < SS*160; i += 512){
    int s = i/160, j2 = i - s*160;          // j2-th u32 (2 elems), 160/row
    unsigned v = 0;
    if (j2 < 150){
      float2 t = *(const float2*)(emb + (size_t)sid[s]*DD + j2*2);
      v = packbf(t.x, t.y);
    }
    *(unsigned*)(a2 + ((size_t)b*SS + s)*320 + j2*2) = v;
  }
}

// ============================ K0b: uv f32 -> bf16 [M][320] ===================
__global__ __launch_bounds__(512) void k0b_conv(
    const float* __restrict__ uv, short* __restrict__ a1, int M)
{
  const int total = M*160;                  // u32 chunks (2 bf16), 160/row
  for (int idx = blockIdx.x*512 + threadIdx.x; idx < total; idx += gridDim.x*512){
    int row = idx/160, j2 = idx - row*160;
    unsigned v = 0;
    if (j2 < 150){
      float2 t = *(const float2*)(uv + (size_t)row*DD + j2*2);
      v = packbf(t.x, t.y);
    }
    *(unsigned*)(a1 + (size_t)row*320 + j2*2) = v;
  }
}

// ============================ K1: tiled GEMM (32x32x16, A in regs) ===========
// 25 slabs x mtiles blocks; round-11 XCD-affine mapping (validated: FETCH 50MB).
// Block: M-tile 128 x N-tile 64. 8 waves = 4M x 2N; wave = 32 rows x 32 cols,
// mfma_f32_32x32x16_bf16, 20 k-steps in 4 batches of 5 (20 VGPR A-live).
// A: per-lane global bf16 loads (L2 hits) from a1 (uv) / a2 (ue); if a1==null,
// uv f32 converted in-lane (fallback). B: staged once in LDS (stride 656).
// ONE barrier. launch_bounds(512,8) -> <=64 VGPR -> full 24-wave residency.
#define G_SM  41984

__global__ __launch_bounds__(512, 8) void k1_gemm(
    const float* __restrict__ uv, const short* __restrict__ a1,
    const short* __restrict__ a2, const short* __restrict__ wsb,
    const float* __restrict__ bq, const float* __restrict__ bk,
    const float* __restrict__ bv, const float* __restrict__ bqp,
    const float* __restrict__ bkp,
    short* __restrict__ qc, short* __restrict__ kc, short* __restrict__ vv,
    short* __restrict__ qp, short* __restrict__ kp,
    int mtiles, int M)
{
  __shared__ __align__(16) unsigned char sm[G_SM];
  const int tid  = threadIdx.x;
  const int bid  = blockIdx.x;
  int slab, mt;
  if ((mtiles & 7) == 0){
    int x = bid & 7, j = bid >> 3;
    int q25 = j / 25;
    mt   = x*(mtiles >> 3) + q25;
    slab = j - q25*25;
  } else {
    slab = bid / mtiles; mt = bid - slab*mtiles;
  }
  const int seg  = slab / 5;
  const int col0 = (slab - seg*5)*64;
  const int row0 = mt*128;

  // ---- stage B slab once: 64 cols x 640B = 2560 x 16B chunks, stride 656 ----
  const short* bsrc = wsb + (size_t)seg*WSEG + (size_t)col0*320;
  for (int i = tid; i < 2560; i += 512){
    int c = i/40, k8 = i - c*40;
    *(float4*)(sm + (unsigned)c*656 + (unsigned)k8*16) =
        *(const float4*)(bsrc + (size_t)c*320 + k8*8);
  }
  __syncthreads();                          // B slab visible; the ONLY barrier
  __builtin_amdgcn_sched_barrier(0);        // pin: nothing crosses the barrier

  const int w = tid >> 6, lane = tid & 63;
  const int l31 = lane & 31, hi = lane >> 5;
  const int mw = w & 3, nw2 = w >> 2;
  const bool segA2 = (seg >= 3);

  int rowA = row0 + mw*32 + l31; if (rowA > M-1) rowA = M-1;
  const unsigned bcol = (unsigned)(nw2*32 + l31)*656u + (unsigned)hi*16u;
  const short* abf = segA2 ? a2 : a1;       // a1 may be null (fallback)
  const short* ap  = abf ? (abf + (size_t)rowA*320 + hi*8) : (const short*)0;
  const float* up  = uv + (size_t)rowA*DD;

  f16t acc = zero16();
  #pragma unroll 1
  for (int batch = 0; batch < 4; ++batch){
    // ---- preload 5 k-steps of this lane's A: k = batch*80 + st*16 + hi*8 ----
    uint4 a[5];
    if (ap){
      #pragma unroll
      for (int st = 0; st < 5; ++st)
        a[st] = *(const uint4*)(ap + batch*80 + st*16);
    } else {
      #pragma unroll
      for (int st = 0; st < 5; ++st){
        int k0e = batch*80 + st*16 + hi*8;
        float v[8];
        if (k0e + 8 <= DD){
          float4 p = *(const float4*)(up + k0e);
          float4 q = *(const float4*)(up + k0e + 4);
          v[0]=p.x; v[1]=p.y; v[2]=p.z; v[3]=p.w;
          v[4]=q.x; v[5]=q.y; v[6]=q.z; v[7]=q.w;
        } else {
          #pragma unroll
          for (int j = 0; j < 8; ++j){
            int kk = k0e + j;
            v[j] = (kk < DD) ? up[kk] : 0.f;
          }
        }
        a[st] = (uint4){ packbf(v[0],v[1]), packbf(v[2],v[3]),
                         packbf(v[4],v[5]), packbf(v[6],v[7]) };
      }
    }
    // ---- 5 x {1 b128 B-read, 1 MFMA 32x32x16} (B read-only; no barriers) ----
    #pragma unroll
    for (int st = 0; st < 5; ++st){
      bf8t bfrag = *(const bf8t*)(sm + bcol + (unsigned)(batch*160 + st*32));
      acc = __builtin_amdgcn_mfma_f32_32x32x16_bf16(*(const bf8t*)&a[st], bfrag, acc, 0, 0, 0);
    }
  }

  // ---- epilogue: bias + bf16 store to natural [M][300] ----
  const float* bias = (seg==0)?bq:(seg==1)?bk:(seg==2)?bv:(seg==3)?bqp:bkp;
  short* outp = (seg==0)?qc:(seg==1)?kc:(seg==2)?vv:(seg==3)?qp:kp;
  const int colseg = col0 + nw2*32 + l31;
  if (colseg < DD){
    float bb = bias[colseg];
    #pragma unroll
    for (int r = 0; r < 16; ++r){
      int row = row0 + mw*32 + (r&3) + 8*(r>>2) + 4*hi;
      if (row < M) outp[(size_t)row*DD + colseg] = (short)f2bf(acc[r] + bb);
    }
  }
}

// ============================ K2: attention ==================================
// block = (b, head-group hg of <=4 heads). LDS:
//   Q [50][192]bf16 stride400 @0 ([Qc20|Qp20|8z] per head)
//   K @20000 ([Ksum20|Kc20|8z], Ksum = Kc+Kp)
//   VT [92][64keys]bf16 stride144 @40000 ; P overlays Q/K: per-wave [32][64] @ w*4608
#define A_Q   0
#define A_K   20000
#define A_VT  40000
#define A_PBLK 4608
#define A_SM  53248

__global__ __launch_bounds__(512) void k2_attn(
    const short* __restrict__ qcg, const short* __restrict__ qpg,
    const short* __restrict__ kcg, const short* __restrict__ kpg,
    const short* __restrict__ vg,  short* __restrict__ cg)
{
  __shared__ __align__(16) unsigned char sm[A_SM];
  const int tid  = threadIdx.x;
  const int bid  = blockIdx.x;
  const int b    = bid >> 2;
  const int hg   = bid & 3;
  const int nheads = (hg < 3) ? 4 : 3;
  const int w    = tid >> 6;
  const int lane = tid & 63;
  const int l31  = lane & 31, hi = lane >> 5;

  // zero VT (keys>=50 must be 0; rows 80..91 finite)
  for (int i = tid; i < 828; i += 512)
    *(float4*)(sm + A_VT + (unsigned)i*16) = make_float4(0.f,0.f,0.f,0.f);
  __syncthreads();
  // stage Q: per (row,hl): [Qc20|Qp20|pad8] (src col clamped for head 15)
  for (int i = tid; i < 4800; i += 512){
    int rhd = i / 24, j = i - rhd*24;
    int row = rhd >> 2, hl = rhd & 3;
    int hc = (hg*4 + hl)*20; if (hc > 280) hc = 280;
    const size_t rbase = ((size_t)b*SS + row)*(size_t)DD + hc;
    unsigned char* ldst = sm + A_Q + (unsigned)row*400 + (unsigned)hl*96;
    if (j < 10)      *(unsigned*)(ldst + j*4)           = *(const unsigned*)(qcg + rbase + j*2);
    else if (j < 20) *(unsigned*)(ldst + 40 + (j-10)*4) = *(const unsigned*)(qpg + rbase + (j-10)*2);
    else             *(unsigned*)(ldst + 80 + (j-20)*4) = 0u;
  }
  // stage K: [Ksum20|Kc20|pad8]
  for (int i = tid; i < 4800; i += 512){
    int rhd = i / 24, j = i - rhd*24;
    int row = rhd >> 2, hl = rhd & 3;
    int hc = (hg*4 + hl)*20; if (hc > 280) hc = 280;
    const size_t rbase = ((size_t)b*SS + row)*(size_t)DD + hc;
    unsigned char* ldst = sm + A_K + (unsigned)row*400 + (unsigned)hl*96;
    if (j < 10){
      unsigned c = *(const unsigned*)(kcg + rbase + j*2);
      unsigned p = *(const unsigned*)(kpg + rbase + j*2);
      *(unsigned*)(ldst + j*4) = packbf(bflo(c)+bflo(p), bfhi(c)+bfhi(p));
    } else if (j < 20){
      *(unsigned*)(ldst + 40 + (j-10)*4) = *(const unsigned*)(kcg + rbase + (j-10)*2);
    } else {
      *(unsigned*)(ldst + 80 + (j-20)*4) = 0u;
    }
  }
  // stage VT (transpose): u32 (2 dims) per (row,d2); src col clamped
  for (int i = tid; i < 2000; i += 512){
    int row = i/40, d2 = i - row*40;
    int col = hg*80 + d2*2; if (col > 298) col = 298;
    unsigned v = *(const unsigned*)(vg + ((size_t)b*SS + row)*(size_t)DD + col);
    *(unsigned short*)(sm + A_VT + (unsigned)(d2*2)*144   + (unsigned)row*2) = (unsigned short)(v & 0xffffu);
    *(unsigned short*)(sm + A_VT + (unsigned)(d2*2+1)*144 + (unsigned)row*2) = (unsigned short)(v >> 16);
  }
  __syncthreads();

  const float rscale = 0.1290994449f;  // 1/sqrt(3*DK)
  const int ahl = w >> 1, rt = w & 1;
  const bool act = (ahl < nheads);
  f16t s0, s1;
  if (act){
    s0 = zero16(); s1 = zero16();
    unsigned aoff = A_Q + (unsigned)(rt*32 + l31)*400 + (unsigned)ahl*96 + (unsigned)hi*16;
    unsigned koff = A_K + (unsigned)l31*400 + (unsigned)ahl*96 + (unsigned)hi*16;
    #pragma unroll
    for (int ks = 0; ks < 3; ++ks){
      bf8t a  = *(const bf8t*)(sm + aoff + ks*32);
      bf8t b0 = *(const bf8t*)(sm + koff + ks*32);
      bf8t b1 = *(const bf8t*)(sm + koff + 32u*400 + ks*32);
      s0 = __builtin_amdgcn_mfma_f32_32x32x16_bf16(a, b0, s0, 0, 0, 0);
      s1 = __builtin_amdgcn_mfma_f32_32x32x16_bf16(a, b1, s1, 0, 0, 0);
    }
  }
  __syncthreads();   // Q/K reads done -> P may overwrite
  if (act){
    const bool m1 = (l31 >= 18);   // key 32+l31 >= 50
    unsigned pb = (unsigned)w*A_PBLK;
    float rinv[16];
    #pragma unroll
    for (int r = 0; r < 16; ++r){
      int lrow = (r&3) + 8*(r>>2) + 4*hi;
      float v0 = s0[r]*rscale;
      float v1 = m1 ? -INFINITY : s1[r]*rscale;
      float mx = fmaxf(v0, v1);
      #pragma unroll
      for (int off = 1; off <= 16; off <<= 1) mx = fmaxf(mx, __shfl_xor(mx, off));
      float e0 = __expf(v0 - mx);
      float e1 = m1 ? 0.f : __expf(v1 - mx);
      float sum = e0 + e1;
      #pragma unroll
      for (int off = 1; off <= 16; off <<= 1) sum += __shfl_xor(sum, off);
      rinv[r] = 1.0f/sum;
      *(unsigned short*)(sm + pb + (unsigned)lrow*144 + (unsigned)l31*2)      = f2bf(e0);
      *(unsigned short*)(sm + pb + (unsigned)lrow*144 + 64 + (unsigned)l31*2) = f2bf(e1);
    }
    f16t c = zero16();
    unsigned pa  = pb + (unsigned)l31*144 + (unsigned)hi*16;
    unsigned vb2 = A_VT + (unsigned)(ahl*HD + l31)*144 + (unsigned)hi*16;
    #pragma unroll
    for (int ks = 0; ks < 4; ++ks){
      bf8t a = *(const bf8t*)(sm + pa + ks*32);
      bf8t v = *(const bf8t*)(sm + vb2 + ks*32);
      c = __builtin_amdgcn_mfma_f32_32x32x16_bf16(a, v, c, 0, 0, 0);
    }
    if (l31 < HD){
      int h = hg*4 + ahl;
      #pragma unroll
      for (int r = 0; r < 16; ++r){
        int q = rt*32 + (r&3) + 8*(r>>2) + 4*hi;
        if (q < SS)
          cg[((size_t)b*SS + q)*DD + h*HD + l31] = (short)f2bf(c[r]*rinv[r]);
      }
    }
  }
}

// ============================ K3: pooling ====================================
#define B_CTX 0
#define B_LG  41984
#define B_A2  44032
#define B_SM  44288

template<int NT, int NCTM>
__device__ __forceinline__ void gemm10(const unsigned char* sm, unsigned abase,
                                       const short* __restrict__ wt,
                                       int lane, int w, f4t (&acc)[NT][4])
{
  const int lm = lane & 15, lg = lane >> 4;
  #pragma unroll
  for (int step = 0; step < 10; ++step){
    bf8t a[4];
    #pragma unroll
    for (int rt = 0; rt < 4; ++rt)
      a[rt] = *(const bf8t*)(sm + abase + (unsigned)(rt*16 + lm)*656u + (unsigned)(step*32 + lg*8)*2u);
    #pragma unroll
    for (int t = 0; t < NT; ++t){
      int ct = w + t*8; if (ct > NCTM) ct = NCTM;
      bf8t bb = *(const bf8t*)(wt + (size_t)(ct*16 + lm)*320 + step*32 + lg*8);
      #pragma unroll
      for (int rt = 0; rt < 4; ++rt)
        acc[t][rt] = __builtin_amdgcn_mfma_f32_16x16x32_bf16(a[rt], bb, acc[t][rt], 0, 0, 0);
    }
  }
}

__global__ __launch_bounds__(512) void k3_pool(
    const short* __restrict__ cg, const short* __restrict__ wsb,
    const float* __restrict__ ba, const float* __restrict__ qa,
    float* __restrict__ out)
{
  __shared__ __align__(16) unsigned char sm[B_SM];
  const int tid  = threadIdx.x;
  const int b    = blockIdx.x;
  const int w    = tid >> 6;
  const int lane = tid & 63;
  const int lm   = lane & 15, lg = lane >> 4;
  const short* waT = wsb + WAOFF;

  for (int i = tid; i < SS*75; i += 512){
    int row = i/75, c = i - row*75;
    uint2 v = *(const uint2*)(cg + ((size_t)b*SS + row)*DD + c*4);
    *(uint2*)(sm + B_CTX + (unsigned)row*656 + (unsigned)c*8) = v;
  }
  for (int i = tid; i < SS*14; i += 512)
    *(unsigned*)(sm + B_CTX + (unsigned)(i/14)*656 + 600u + (unsigned)(i%14)*4) = 0;
  __syncthreads();

  {
    f4t accp[2][4];
    #pragma unroll
    for (int t = 0; t < 2; ++t)
      #pragma unroll
      for (int r = 0; r < 4; ++r) accp[t][r] = (f4t){0.f,0.f,0.f,0.f};
    gemm10<2,12>(sm, B_CTX, waT, lane, w, accp);
    float part[4][4];
    #pragma unroll
    for (int rt2 = 0; rt2 < 4; ++rt2)
      #pragma unroll
      for (int i = 0; i < 4; ++i) part[rt2][i] = 0.f;
    #pragma unroll
    for (int t = 0; t < 2; ++t){
      int ct = w + t*8; if (ct > 12) ct = 12;
      bool valid = (t == 0) || (w < 5);
      int col = ct*16 + lm;
      float bav = (col < QDIM) ? ba[col] : 0.f;
      float qav = (valid && col < QDIM) ? qa[col] : 0.f;
      #pragma unroll
      for (int rt2 = 0; rt2 < 4; ++rt2)
        #pragma unroll
        for (int i = 0; i < 4; ++i)
          part[rt2][i] += tanhf(accp[t][rt2][i] + bav) * qav;
    }
    #pragma unroll
    for (int off = 1; off <= 8; off <<= 1)
      #pragma unroll
      for (int rt2 = 0; rt2 < 4; ++rt2)
        #pragma unroll
        for (int i = 0; i < 4; ++i)
          part[rt2][i] += __shfl_xor(part[rt2][i], off);
    if (lm == 0){
      #pragma unroll
      for (int rt2 = 0; rt2 < 4; ++rt2)
        #pragma unroll
        for (int i = 0; i < 4; ++i){
          int row = rt2*16 + lg*4 + i;
          if (row < SS) *(float*)(sm + B_LG + (unsigned)(row*8 + w)*4) = part[rt2][i];
        }
    }
  }
  __syncthreads();
  if (w == 0){
    const int sl = lane < SS ? lane : SS - 1;
    const bool rowok = lane < SS;
    float lgv = -INFINITY;
    if (rowok){
      float s = 0.f;
      #pragma unroll
      for (int j = 0; j < 8; ++j) s += *(const float*)(sm + B_LG + (unsigned)(sl*8 + j)*4);
      lgv = s;
    }
    float m = lgv;
    #pragma unroll
    for (int off = 32; off; off >>= 1) m = fmaxf(m, __shfl_xor(m, off));
    float e = rowok ? __expf(lgv - m) : 0.f;
    float ssum = e;
    #pragma unroll
    for (int off = 32; off; off >>= 1) ssum += __shfl_xor(ssum, off);
    *(float*)(sm + B_A2 + lane*4) = e / ssum;
  }
  __syncthreads();
  if (tid < DD){
    float accv = 0.f;
    for (int s = 0; s < SS; ++s){
      float av = *(const float*)(sm + B_A2 + (unsigned)s*4);
      unsigned short cv = *(const unsigned short*)(sm + B_CTX + (unsigned)s*656 + (unsigned)tid*2);
      accv = fmaf(av, __uint_as_float((unsigned)cv << 16), accv);
    }
    out[(size_t)b*DD + tid] = accv;
  }
}

// ===================== fallback: round-4 fused kernel ========================
#define OFF_UV  0
#define OFF_UE  32800
#define QKSTR   400
#define OFF_Q   65600
#define OFF_K   85600
#define OFF_P   65600
#define PBLK    4608
#define PSTR    144
#define VTSTR   144
#define OFF_VT  105600
#define OFF_CTX 117120
#define OFF_LG  159104
#define OFF_A2  161152
#define OFF_IDS 161408
#define SM_TOTAL 161616

__global__ __launch_bounds__(512) void user_enc_kernel(
    const int*   __restrict__ ids, const float* __restrict__ uv,
    const float* __restrict__ emb,
    const float* __restrict__ bq, const float* __restrict__ bk,
    const float* __restrict__ bv, const float* __restrict__ bqp,
    const float* __restrict__ bkp,
    const float* __restrict__ ba, const float* __restrict__ qa,
    const short* __restrict__ wsb, float* __restrict__ out)
{
  __shared__ __align__(16) unsigned char sm[SM_TOTAL];
  const int tid  = threadIdx.x;
  const int b    = blockIdx.x;
  const int w    = tid >> 6;
  const int lane = tid & 63;
  const int lm   = lane & 15, lg = lane >> 4;
  const int l31  = lane & 31, hi = lane >> 5;

  const short* wqT  = wsb;
  const short* wkT  = wsb + WSEG;
  const short* wvT  = wsb + 2*WSEG;
  const short* wqpT = wsb + 3*WSEG;
  const short* wkpT = wsb + 4*WSEG;
  const short* waT  = wsb + WAOFF;

  if (tid < SS) *(int*)(sm + OFF_IDS + tid*4) = ids[(size_t)b*SS + tid];
  {
    const float* srcv = uv + (size_t)b*SS*DD;
    for (int i = tid; i < SS*75; i += 512){
      int s = i/75, j4 = i - s*75;
      float4 v = *(const float4*)(srcv + s*DD + j4*4);
      *(unsigned*)(sm + OFF_UV + (unsigned)s*656 + (unsigned)j4*8)     = packbf(v.x, v.y);
      *(unsigned*)(sm + OFF_UV + (unsigned)s*656 + (unsigned)j4*8 + 4) = packbf(v.z, v.w);
    }
    for (int i = tid; i < SS*28; i += 512){
      int s = i/28, j = i - s*28;
      unsigned off = (j < 14) ? (OFF_UV + (unsigned)s*656 + 600u + (unsigned)j*4)
                              : (OFF_UE + (unsigned)s*656 + 600u + (unsigned)(j-14)*4);
      *(unsigned*)(sm + off) = 0;
    }
    for (int i = tid; i < SS*14; i += 512)
      *(unsigned*)(sm + OFF_CTX + (unsigned)(i/14)*656 + 600u + (unsigned)(i%14)*4) = 0;
    for (int i = tid; i < 720; i += 512)
      *(float4*)(sm + OFF_VT + (unsigned)i*16) = make_float4(0.f,0.f,0.f,0.f);
  }
  __syncthreads();
  for (int i = tid; i < SS*75; i += 512){
    int s = i/75, j4 = i - s*75;
    int id = *(const int*)(sm + OFF_IDS + s*4);
    float4 v = *(const float4*)(emb + (size_t)id*DD + j4*4);
    *(unsigned*)(sm + OFF_UE + (unsigned)s*656 + (unsigned)j4*8)     = packbf(v.x, v.y);
    *(unsigned*)(sm + OFF_UE + (unsigned)s*656 + (unsigned)j4*8 + 4) = packbf(v.z, v.w);
  }

  const float rscale = 0.1290994449f;
  #pragma unroll 1
  for (int nb4 = 0; nb4 < 4; ++nb4){
    const int nheads = (nb4 < 3) ? 4 : 3;
    const int NCT    = (nb4 < 3) ? 5 : 4;
    __syncthreads();
    for (int i = tid; i < SS*4; i += 512){
      int r = i >> 2, hl0 = i & 3;
      *(float4*)(sm + OFF_Q + (unsigned)r*QKSTR + (unsigned)hl0*96 + 80) = make_float4(0.f,0.f,0.f,0.f);
      *(float4*)(sm + OFF_K + (unsigned)r*QKSTR + (unsigned)hl0*96 + 80) = make_float4(0.f,0.f,0.f,0.f);
    }
    for (int ht = w; ht < 8*NCT; ht += 8){
      const int g   = (ht >= 6*NCT) ? 3 : (ht >= 4*NCT) ? 2 : (ht >= 2*NCT) ? 1 : 0;
      const int rem = ht - g*2*NCT;
      const int c   = rem >> 1, rh = rem & 1;
      const int col = nb4*80 + c*16 + lm;
      const int colc = (col < DD) ? col : DD-1;
      const int head = col / HD;
      const int dd   = col - head*HD;
      const int hl   = head - nb4*4;
      const bool valid = (hl < nheads) && (col < DD);
      const unsigned abase = (g == 1) ? (unsigned)OFF_UE : (unsigned)OFF_UV;
      const short* wt = (g==0) ? wqT : (g==1) ? wqpT : (g==2) ? wvT : wkT;
      const short* wb = wt + (size_t)col*320 + lg*8;
      f4t a0 = {0.f,0.f,0.f,0.f}, a1 = {0.f,0.f,0.f,0.f};
      #pragma unroll
      for (int st = 0; st < 10; ++st){
        bf8t bb = *(const bf8t*)(wb + st*32);
        bf8t x0 = *(const bf8t*)(sm + abase + (unsigned)(rh*32 + lm)*656u + (unsigned)(st*32 + lg*8)*2u);
        bf8t x1 = *(const bf8t*)(sm + abase + (unsigned)(rh*32 + 16 + lm)*656u + (unsigned)(st*32 + lg*8)*2u);
        a0 = __builtin_amdgcn_mfma_f32_16x16x32_bf16(x0, bb, a0, 0, 0, 0);
        a1 = __builtin_amdgcn_mfma_f32_16x16x32_bf16(x1, bb, a1, 0, 0, 0);
      }
      if (g == 2){
        if (valid){
          float bias = bv[colc];
          unsigned vb = OFF_VT + (unsigned)(hl*HD + dd)*VTSTR;
          int r0 = rh*32 + lg*4;
          if (r0 < SS){
            *(unsigned*)(sm + vb + (unsigned)r0*2) = packbf(a0[0]+bias, a0[1]+bias);
            if (r0+2 < SS) *(unsigned*)(sm + vb + (unsigned)r0*2 + 4) = packbf(a0[2]+bias, a0[3]+bias);
          }
          int r1 = rh*32 + 16 + lg*4;
          if (r1 < SS){
            *(unsigned*)(sm + vb + (unsigned)r1*2) = packbf(a1[0]+bias, a1[1]+bias);
            if (r1+2 < SS) *(unsigned*)(sm + vb + (unsigned)r1*2 + 4) = packbf(a1[2]+bias, a1[3]+bias);
          }
        }
      } else if (g != 3){
        if (valid){
          float bias = (g==0) ? bq[colc] : bqp[colc];
          unsigned qb = OFF_Q + (unsigned)hl*96 + (unsigned)dd*2 + (g==1 ? 40u : 0u);
          #pragma unroll
          for (int i = 0; i < 4; ++i){
            int r0 = rh*32 + lg*4 + i;
            if (r0 < SS) *(unsigned short*)(sm + qb + (unsigned)r0*QKSTR) = f2bf(a0[i]+bias);
            int r1 = rh*32 + 16 + lg*4 + i;
            if (r1 < SS) *(unsigned short*)(sm + qb + (unsigned)r1*QKSTR) = f2bf(a1[i]+bias);
          }
        }
      } else {
        float bkc = bk[colc];
        if (valid){
          unsigned kb = OFF_K + (unsigned)hl*96 + (unsigned)dd*2 + 40u;
          #pragma unroll
          for (int i = 0; i < 4; ++i){
            int r0 = rh*32 + lg*4 + i;
            if (r0 < SS) *(unsigned short*)(sm + kb + (unsigned)r0*QKSTR) = f2bf(a0[i]+bkc);
            int r1 = rh*32 + 16 + lg*4 + i;
            if (r1 < SS) *(unsigned short*)(sm + kb + (unsigned)r1*QKSTR) = f2bf(a1[i]+bkc);
          }
        }
        const short* wb2 = wkpT + (size_t)col*320 + lg*8;
        #pragma unroll
        for (int st = 0; st < 10; ++st){
          bf8t bb = *(const bf8t*)(wb2 + st*32);
          bf8t x0 = *(const bf8t*)(sm + OFF_UE + (unsigned)(rh*32 + lm)*656u + (unsigned)(st*32 + lg*8)*2u);
          bf8t x1 = *(const bf8t*)(sm + OFF_UE + (unsigned)(rh*32 + 16 + lm)*656u + (unsigned)(st*32 + lg*8)*2u);
          a0 = __builtin_amdgcn_mfma_f32_16x16x32_bf16(x0, bb, a0, 0, 0, 0);
          a1 = __builtin_amdgcn_mfma_f32_16x16x32_bf16(x1, bb, a1, 0, 0, 0);
        }
        if (valid){
          float bsum = bkc + bkp[colc];
          unsigned kb = OFF_K + (unsigned)hl*96 + (unsigned)dd*2;
          #pragma unroll
          for (int i = 0; i < 4; ++i){
            int r0 = rh*32 + lg*4 + i;
            if (r0 < SS) *(unsigned short*)(sm + kb + (unsigned)r0*QKSTR) = f2bf(a0[i]+bsum);
            int r1 = rh*32 + 16 + lg*4 + i;
            if (r1 < SS) *(unsigned short*)(sm + kb + (unsigned)r1*QKSTR) = f2bf(a1[i]+bsum);
          }
        }
      }
    }
    __syncthreads();
    const int ahl = w >> 1, rt = w & 1;
    const bool act = (ahl < nheads);
    f16t s0, s1;
    if (act){
      s0 = zero16(); s1 = zero16();
      unsigned aoff = OFF_Q + (unsigned)(rt*32 + l31)*QKSTR + (unsigned)ahl*96 + (unsigned)hi*16;
      unsigned koff = OFF_K + (unsigned)l31*QKSTR + (unsigned)ahl*96 + (unsigned)hi*16;
      #pragma unroll
      for (int ks = 0; ks < 3; ++ks){
        bf8t a  = *(const bf8t*)(sm + aoff + ks*32);
        bf8t b0 = *(const bf8t*)(sm + koff + ks*32);
        bf8t b1 = *(const bf8t*)(sm + koff + 32u*QKSTR + ks*32);
        s0 = __builtin_amdgcn_mfma_f32_32x32x16_bf16(a, b0, s0, 0, 0, 0);
        s1 = __builtin_amdgcn_mfma_f32_32x32x16_bf16(a, b1, s1, 0, 0, 0);
      }
    }
    __syncthreads();
    if (act){
      const bool m1 = (l31 >= 18);
      unsigned pb = OFF_P + (unsigned)w*PBLK;
      float rinv[16];
      #pragma unroll
      for (int r = 0; r < 16; ++r){
        int lrow = (r&3) + 8*(r>>2) + 4*hi;
        float v0 = s0[r]*rscale;
        float v1 = m1 ? -INFINITY : s1[r]*rscale;
        float mx = fmaxf(v0, v1);
        #pragma unroll
        for (int off = 1; off <= 16; off <<= 1) mx = fmaxf(mx, __shfl_xor(mx, off));
        float e0 = __expf(v0 - mx);
        float e1 = m1 ? 0.f : __expf(v1 - mx);
        float sum = e0 + e1;
        #pragma unroll
        for (int off = 1; off <= 16; off <<= 1) sum += __shfl_xor(sum, off);
        rinv[r] = 1.0f/sum;
        *(unsigned short*)(sm + pb + (unsigned)lrow*PSTR + (unsigned)l31*2)      = f2bf(e0);
        *(unsigned short*)(sm + pb + (unsigned)lrow*PSTR + 64 + (unsigned)l31*2) = f2bf(e1);
      }
      f16t c = zero16();
      unsigned pa  = pb + (unsigned)l31*PSTR + (unsigned)hi*16;
      unsigned vb2 = OFF_VT + (unsigned)(ahl*HD + l31)*VTSTR + (unsigned)hi*16;
      #pragma unroll
      for (int ks = 0; ks < 4; ++ks){
        bf8t a = *(const bf8t*)(sm + pa + ks*32);
        bf8t v = *(const bf8t*)(sm + vb2 + ks*32);
        c = __builtin_amdgcn_mfma_f32_32x32x16_bf16(a, v, c, 0, 0, 0);
      }
      if (l31 < HD){
        int h = nb4*4 + ahl;
        #pragma unroll
        for (int r = 0; r < 16; ++r){
          int q = rt*32 + (r&3) + 8*(r>>2) + 4*hi;
          if (q < SS)
            *(unsigned short*)(sm + OFF_CTX + (unsigned)q*656 + (unsigned)(h*HD + l31)*2) =
                f2bf(c[r]*rinv[r]);
        }
      }
    }
  }
  __syncthreads();

  {
    f4t accp[2][4];
    #pragma unroll
    for (int t = 0; t < 2; ++t)
      #pragma unroll
      for (int r = 0; r < 4; ++r) accp[t][r] = (f4t){0.f,0.f,0.f,0.f};
    gemm10<2,12>(sm, OFF_CTX, waT, lane, w, accp);
    float part[4][4];
    #pragma unroll
    for (int rt2 = 0; rt2 < 4; ++rt2)
      #pragma unroll
      for (int i = 0; i < 4; ++i) part[rt2][i] = 0.f;
    #pragma unroll
    for (int t = 0; t < 2; ++t){
      int ct = w + t*8; if (ct > 12) ct = 12;
      bool valid = (t == 0) || (w < 5);
      int col = ct*16 + lm;
      float bav = (col < QDIM) ? ba[col] : 0.f;
      float qav = (valid && col < QDIM) ? qa[col] : 0.f;
      #pragma unroll
      for (int rt2 = 0; rt2 < 4; ++rt2)
        #pragma unroll
        for (int i = 0; i < 4; ++i)
          part[rt2][i] += tanhf(accp[t][rt2][i] + bav) * qav;
    }
    #pragma unroll
    for (int off = 1; off <= 8; off <<= 1)
      #pragma unroll
      for (int rt2 = 0; rt2 < 4; ++rt2)
        #pragma unroll
        for (int i = 0; i < 4; ++i)
          part[rt2][i] += __shfl_xor(part[rt2][i], off);
    if (lm == 0){
      #pragma unroll
      for (int rt2 = 0; rt2 < 4; ++rt2)
        #pragma unroll
        for (int i = 0; i < 4; ++i){
          int row = rt2*16 + lg*4 + i;
          if (row < SS) *(float*)(sm + OFF_LG + (unsigned)(row*8 + w)*4) = part[rt2][i];
        }
    }
  }
  __syncthreads();
  if (w == 0){
    const int sl = lane < SS ? lane : SS - 1;
    const bool rowok = lane < SS;
    float lgv = -INFINITY;
    if (rowok){
      float s = 0.f;
      #pragma unroll
      for (int j = 0; j < 8; ++j) s += *(const float*)(sm + OFF_LG + (unsigned)(sl*8 + j)*4);
      lgv = s;
    }
    float m = lgv;
    #pragma unroll
    for (int off = 32; off; off >>= 1) m = fmaxf(m, __shfl_xor(m, off));
    float e = rowok ? __expf(lgv - m) : 0.f;
    float ssum = e;
    #pragma unroll
    for (int off = 32; off; off >>= 1) ssum += __shfl_xor(ssum, off);
    *(float*)(sm + OFF_A2 + lane*4) = e / ssum;
  }
  __syncthreads();
  if (tid < DD){
    float accv = 0.f;
    for (int s = 0; s < SS; ++s){
      float av = *(const float*)(sm + OFF_A2 + (unsigned)s*4);
      unsigned short cv = *(const unsigned short*)(sm + OFF_CTX + (unsigned)s*656 + (unsigned)tid*2);
      accv = fmaf(av, __uint_as_float((unsigned)cv << 16), accv);
    }
    out[(size_t)b*DD + tid] = accv;
  }
}

extern "C" void kernel_launch(void* const* d_in, const int* in_sizes, int n_in,
                              void* d_out, int out_size, void* d_ws, size_t ws_size,
                              hipStream_t stream){
  (void)n_in; (void)out_size;
  const int*   ids = (const int*)  d_in[0];
  const float* uvp = (const float*)d_in[1];
  const float* emb = (const float*)d_in[2];
  const float* Wq  = (const float*)d_in[3];
  const float* bq  = (const float*)d_in[4];
  const float* Wk  = (const float*)d_in[5];
  const float* bk  = (const float*)d_in[6];
  const float* Wv  = (const float*)d_in[7];
  const float* bv  = (const float*)d_in[8];
  const float* Wqp = (const float*)d_in[9];
  const float* bqp = (const float*)d_in[10];
  const float* Wkp = (const float*)d_in[11];
  const float* bkp = (const float*)d_in[12];
  const float* Wa  = (const float*)d_in[13];
  const float* ba  = (const float*)d_in[14];
  const float* qa  = (const float*)d_in[15];
  short* wsb = (short*)d_ws;

  const int nb = in_sizes[0] / SS;   // 1024
  const int M  = nb * SS;            // 51200
  const int mtiles = (M + 127) / 128;

  // ws layouts (bf16 elems):
  //   with a1:    weights | a1 [M][320] | a2 [M][320] | 5 x C [M][300]
  //   without a1: weights |               a2 [M][320] | 5 x C [M][300]
  const size_t AELEM = (size_t)M * 320;
  const size_t CELEM = (size_t)M * DD;
  const size_t needA = (WTOT + 2*AELEM + 5*CELEM) * 2;
  const size_t needB = (WTOT +   AELEM + 5*CELEM) * 2;

  conv_weights<<<(WTOT + 255)/256, 256, 0, stream>>>(Wq, Wk, Wv, Wqp, Wkp, Wa, wsb);

  if (ws_size >= needB){
    const bool hasA1 = (ws_size >= needA);
    short* a1  = hasA1 ? (wsb + WTOT) : nullptr;
    short* a2  = wsb + WTOT + (hasA1 ? AELEM : 0);
    short* qcg = a2 + AELEM;
    short* kcg = qcg + CELEM;
    short* vg  = kcg + CELEM;
    short* qpg = vg  + CELEM;
    short* kpg = qpg + CELEM;
    short* cg  = a2;   // alias: a2 dead after k1

    k0_gather<<<nb, 512, 0, stream>>>(ids, emb, a2);
    if (hasA1) k0b_conv<<<2048, 512, 0, stream>>>(uvp, a1, M);
    k1_gemm<<<25*mtiles, 512, 0, stream>>>(uvp, (const short*)a1, (const short*)a2,
                                           (const short*)wsb,
                                           bq, bk, bv, bqp, bkp,
                                           qcg, kcg, vg, qpg, kpg, mtiles, M);
    k2_attn<<<nb*4, 512, 0, stream>>>((const short*)qcg, (const short*)qpg,
                                      (const short*)kcg, (const short*)kpg,
                                      (const short*)vg, cg);
    k3_pool<<<nb, 512, 0, stream>>>((const short*)cg, (const short*)wsb,
                                    ba, qa, (float*)d_out);
  } else {
    user_enc_kernel<<<nb, 512, 0, stream>>>(ids, uvp, emb,
                                            bq, bk, bv, bqp, bkp, ba, qa,
                                            (const short*)wsb, (float*)d_out);
  }
}

// Round 16
// 364.761 us; speedup vs baseline: 2.2572x; 1.1901x over previous
//
#include <hip/hip_runtime.h>
#include <hip/hip_bf16.h>

#define SS   50     // sequence length
#define DD   300    // embedding dim
#define NH   15     // heads
#define HD   20     // per-head dim
#define QDIM 200    // additive attention dim

// ws (bf16 elements): 5 proj [304][320] + Wa [208][320]
#define WSEG  97280
#define WAOFF 486400
#define WTOT  552960

typedef __attribute__((ext_vector_type(8)))  short bf8t;
typedef __attribute__((ext_vector_type(4)))  float f4t;
typedef __attribute__((ext_vector_type(16))) float f16t;

__device__ __forceinline__ float bflo(unsigned p){ return __uint_as_float(p << 16); }
__device__ __forceinline__ float bfhi(unsigned p){ return __uint_as_float(p & 0xffff0000u); }
__device__ __forceinline__ unsigned short f2bf(float x){
  unsigned u = __float_as_uint(x);
  return (unsigned short)((u + 0x7fffu + ((u >> 16) & 1u)) >> 16);
}
__device__ __forceinline__ unsigned packbf(float a, float b){
  return (unsigned)f2bf(a) | ((unsigned)f2bf(b) << 16);
}
__device__ __forceinline__ f16t zero16(){
  f16t v;
  #pragma unroll
  for (int i = 0; i < 16; ++i) v[i] = 0.f;
  return v;
}

// ---------------- weight converter: f32 [300][N] -> bf16 [Npad][320] (B^T, zero-padded)
__global__ __launch_bounds__(256) void conv_weights(
    const float* __restrict__ Wq, const float* __restrict__ Wk,
    const float* __restrict__ Wv, const float* __restrict__ Wqp,
    const float* __restrict__ Wkp, const float* __restrict__ Wa,
    short* __restrict__ ws)
{
  int idx = blockIdx.x*256 + threadIdx.x;
  if (idx >= WTOT) return;
  float v = 0.f;
  if (idx < WAOFF){
    int seg = idx / WSEG, r = idx - seg*WSEG;
    int n = r / 320, k = r - n*320;
    const float* W = (seg==0)?Wq:(seg==1)?Wk:(seg==2)?Wv:(seg==3)?Wqp:Wkp;
    if (n < DD && k < DD) v = W[k*DD + n];
  } else {
    int r = idx - WAOFF;
    int n = r / 320, k = r - n*320;
    if (n < QDIM && k < DD) v = Wa[k*QDIM + n];
  }
  ws[idx] = (short)f2bf(v);
}

// ============================ K0: ue gather -> bf16 [M][320] =================
__global__ __launch_bounds__(512) void k0_gather(
    const int* __restrict__ ids, const float* __restrict__ emb,
    short* __restrict__ a2)
{
  __shared__ int sid[SS];
  const int tid = threadIdx.x, b = blockIdx.x;
  if (tid < SS) sid[tid] = ids[(size_t)b*SS + tid];
  __syncthreads();
  for (int i = tid; i < SS*160; i += 512){
    int s = i/160, j2 = i - s*160;          // j2-th u32 (2 elems), 160/row
    unsigned v = 0;
    if (j2 < 150){
      float2 t = *(const float2*)(emb + (size_t)sid[s]*DD + j2*2);
      v = packbf(t.x, t.y);
    }
    *(unsigned*)(a2 + ((size_t)b*SS + s)*320 + j2*2) = v;
  }
}

// ============================ K0b: uv f32 -> bf16 [M][320] ===================
__global__ __launch_bounds__(512) void k0b_conv(
    const float* __restrict__ uv, short* __restrict__ a1, int M)
{
  const int total = M*160;                  // u32 chunks (2 bf16), 160/row
  for (int idx = blockIdx.x*512 + threadIdx.x; idx < total; idx += gridDim.x*512){
    int row = idx/160, j2 = idx - row*160;
    unsigned v = 0;
    if (j2 < 150){
      float2 t = *(const float2*)(uv + (size_t)row*DD + j2*2);
      v = packbf(t.x, t.y);
    }
    *(unsigned*)(a1 + (size_t)row*320 + j2*2) = v;
  }
}

// ============================ K1: tiled GEMM (32x32x16, wave = 32x64) ========
// 25 slabs x mtiles blocks; XCD-affine mapping (mtiles=200 divisible by 8 ->
// bijective; all slabs of one M-range co-schedule on one XCD, A+B L2-hit).
// Block: M-tile 256 x N-tile 64. 8 waves = 8 row-strips of 32; each wave owns
// ALL 64 cols (2 MFMA col-tiles -> A read ONCE per block, B amortized 2x).
// A: per-lane bf16 global loads (L2) in 4 batches of 5 (20 VGPR); B staged
// once in LDS (stride 656, conflict-free measured). ONE barrier total.
#define G_SM  41984

__global__ __launch_bounds__(512, 6) void k1_gemm(
    const float* __restrict__ uv, const short* __restrict__ a1,
    const short* __restrict__ a2, const short* __restrict__ wsb,
    const float* __restrict__ bq, const float* __restrict__ bk,
    const float* __restrict__ bv, const float* __restrict__ bqp,
    const float* __restrict__ bkp,
    short* __restrict__ qc, short* __restrict__ kc, short* __restrict__ vv,
    short* __restrict__ qp, short* __restrict__ kp,
    int mtiles, int M)
{
  __shared__ __align__(16) unsigned char sm[G_SM];
  const int tid  = threadIdx.x;
  const int bid  = blockIdx.x;
  int slab, mt;
  if ((mtiles & 7) == 0){
    int x = bid & 7, j = bid >> 3;
    int q25 = j / 25;
    mt   = x*(mtiles >> 3) + q25;
    slab = j - q25*25;
  } else {
    slab = bid / mtiles; mt = bid - slab*mtiles;
  }
  const int seg  = slab / 5;
  const int col0 = (slab - seg*5)*64;
  const int row0 = mt*256;

  // ---- stage B slab once: 64 cols x 640B = 2560 x 16B chunks, stride 656 ----
  const short* bsrc = wsb + (size_t)seg*WSEG + (size_t)col0*320;
  for (int i = tid; i < 2560; i += 512){
    int c = i/40, k8 = i - c*40;
    *(float4*)(sm + (unsigned)c*656 + (unsigned)k8*16) =
        *(const float4*)(bsrc + (size_t)c*320 + k8*8);
  }
  __syncthreads();                          // B slab visible; the ONLY barrier
  __builtin_amdgcn_sched_barrier(0);        // pin: nothing crosses the barrier

  const int w = tid >> 6, lane = tid & 63;
  const int l31 = lane & 31, hi = lane >> 5;
  const bool segA2 = (seg >= 3);

  int rowA = row0 + w*32 + l31; if (rowA > M-1) rowA = M-1;
  const unsigned bcol0 = (unsigned)l31*656u + (unsigned)hi*16u;        // cols col0+0..31
  const unsigned bcol1 = (unsigned)(32 + l31)*656u + (unsigned)hi*16u; // cols col0+32..63
  const short* abf = segA2 ? a2 : a1;       // a1 may be null (fallback)
  const short* ap  = abf ? (abf + (size_t)rowA*320 + hi*8) : (const short*)0;
  const float* up  = uv + (size_t)rowA*DD;

  f16t acc0 = zero16(), acc1 = zero16();
  #pragma unroll 1
  for (int batch = 0; batch < 4; ++batch){
    // ---- preload 5 k-steps of this lane's A: k = batch*80 + st*16 + hi*8 ----
    uint4 a[5];
    if (ap){
      #pragma unroll
      for (int st = 0; st < 5; ++st)
        a[st] = *(const uint4*)(ap + batch*80 + st*16);
    } else {
      #pragma unroll
      for (int st = 0; st < 5; ++st){
        int k0e = batch*80 + st*16 + hi*8;
        float v[8];
        if (k0e + 8 <= DD){
          float4 p = *(const float4*)(up + k0e);
          float4 q = *(const float4*)(up + k0e + 4);
          v[0]=p.x; v[1]=p.y; v[2]=p.z; v[3]=p.w;
          v[4]=q.x; v[5]=q.y; v[6]=q.z; v[7]=q.w;
        } else {
          #pragma unroll
          for (int j = 0; j < 8; ++j){
            int kk = k0e + j;
            v[j] = (kk < DD) ? up[kk] : 0.f;
          }
        }
        a[st] = (uint4){ packbf(v[0],v[1]), packbf(v[2],v[3]),
                         packbf(v[4],v[5]), packbf(v[6],v[7]) };
      }
    }
    // ---- 5 x {2 b128 B-reads, 2 MFMA 32x32x16} (B read-only; no barriers) ----
    #pragma unroll
    for (int st = 0; st < 5; ++st){
      unsigned ko = (unsigned)(batch*160 + st*32);
      bf8t af = *(const bf8t*)&a[st];
      bf8t b0 = *(const bf8t*)(sm + bcol0 + ko);
      bf8t b1 = *(const bf8t*)(sm + bcol1 + ko);
      acc0 = __builtin_amdgcn_mfma_f32_32x32x16_bf16(af, b0, acc0, 0, 0, 0);
      acc1 = __builtin_amdgcn_mfma_f32_32x32x16_bf16(af, b1, acc1, 0, 0, 0);
    }
  }

  // ---- epilogue: bias + bf16 store to natural [M][300] ----
  const float* bias = (seg==0)?bq:(seg==1)?bk:(seg==2)?bv:(seg==3)?bqp:bkp;
  short* outp = (seg==0)?qc:(seg==1)?kc:(seg==2)?vv:(seg==3)?qp:kp;
  #pragma unroll
  for (int ct = 0; ct < 2; ++ct){
    const f16t& acc = ct ? acc1 : acc0;
    int colseg = col0 + ct*32 + l31;
    if (colseg < DD){
      float bb = bias[colseg];
      #pragma unroll
      for (int r = 0; r < 16; ++r){
        int row = row0 + w*32 + (r&3) + 8*(r>>2) + 4*hi;
        if (row < M) outp[(size_t)row*DD + colseg] = (short)f2bf(acc[r] + bb);
      }
    }
  }
}

// ============================ K2: attention ==================================
// block = (b, head-group hg of <=4 heads). LDS:
//   Q [50][192]bf16 stride400 @0 ([Qc20|Qp20|8z] per head)
//   K @20000 ([Ksum20|Kc20|8z], Ksum = Kc+Kp)
//   VT [92][64keys]bf16 stride144 @40000 ; P overlays Q/K: per-wave [32][64] @ w*4608
#define A_Q   0
#define A_K   20000
#define A_VT  40000
#define A_PBLK 4608
#define A_SM  53248

__global__ __launch_bounds__(512) void k2_attn(
    const short* __restrict__ qcg, const short* __restrict__ qpg,
    const short* __restrict__ kcg, const short* __restrict__ kpg,
    const short* __restrict__ vg,  short* __restrict__ cg)
{
  __shared__ __align__(16) unsigned char sm[A_SM];
  const int tid  = threadIdx.x;
  const int bid  = blockIdx.x;
  const int b    = bid >> 2;
  const int hg   = bid & 3;
  const int nheads = (hg < 3) ? 4 : 3;
  const int w    = tid >> 6;
  const int lane = tid & 63;
  const int l31  = lane & 31, hi = lane >> 5;

  // zero VT (keys>=50 must be 0; rows 80..91 finite)
  for (int i = tid; i < 828; i += 512)
    *(float4*)(sm + A_VT + (unsigned)i*16) = make_float4(0.f,0.f,0.f,0.f);
  __syncthreads();
  // stage Q: per (row,hl): [Qc20|Qp20|pad8] (src col clamped for head 15)
  for (int i = tid; i < 4800; i += 512){
    int rhd = i / 24, j = i - rhd*24;
    int row = rhd >> 2, hl = rhd & 3;
    int hc = (hg*4 + hl)*20; if (hc > 280) hc = 280;
    const size_t rbase = ((size_t)b*SS + row)*(size_t)DD + hc;
    unsigned char* ldst = sm + A_Q + (unsigned)row*400 + (unsigned)hl*96;
    if (j < 10)      *(unsigned*)(ldst + j*4)           = *(const unsigned*)(qcg + rbase + j*2);
    else if (j < 20) *(unsigned*)(ldst + 40 + (j-10)*4) = *(const unsigned*)(qpg + rbase + (j-10)*2);
    else             *(unsigned*)(ldst + 80 + (j-20)*4) = 0u;
  }
  // stage K: [Ksum20|Kc20|pad8]
  for (int i = tid; i < 4800; i += 512){
    int rhd = i / 24, j = i - rhd*24;
    int row = rhd >> 2, hl = rhd & 3;
    int hc = (hg*4 + hl)*20; if (hc > 280) hc = 280;
    const size_t rbase = ((size_t)b*SS + row)*(size_t)DD + hc;
    unsigned char* ldst = sm + A_K + (unsigned)row*400 + (unsigned)hl*96;
    if (j < 10){
      unsigned c = *(const unsigned*)(kcg + rbase + j*2);
      unsigned p = *(const unsigned*)(kpg + rbase + j*2);
      *(unsigned*)(ldst + j*4) = packbf(bflo(c)+bflo(p), bfhi(c)+bfhi(p));
    } else if (j < 20){
      *(unsigned*)(ldst + 40 + (j-10)*4) = *(const unsigned*)(kcg + rbase + (j-10)*2);
    } else {
      *(unsigned*)(ldst + 80 + (j-20)*4) = 0u;
    }
  }
  // stage VT (transpose): u32 (2 dims) per (row,d2); src col clamped
  for (int i = tid; i < 2000; i += 512){
    int row = i/40, d2 = i - row*40;
    int col = hg*80 + d2*2; if (col > 298) col = 298;
    unsigned v = *(const unsigned*)(vg + ((size_t)b*SS + row)*(size_t)DD + col);
    *(unsigned short*)(sm + A_VT + (unsigned)(d2*2)*144   + (unsigned)row*2) = (unsigned short)(v & 0xffffu);
    *(unsigned short*)(sm + A_VT + (unsigned)(d2*2+1)*144 + (unsigned)row*2) = (unsigned short)(v >> 16);
  }
  __syncthreads();

  const float rscale = 0.1290994449f;  // 1/sqrt(3*DK)
  const int ahl = w >> 1, rt = w & 1;
  const bool act = (ahl < nheads);
  f16t s0, s1;
  if (act){
    s0 = zero16(); s1 = zero16();
    unsigned aoff = A_Q + (unsigned)(rt*32 + l31)*400 + (unsigned)ahl*96 + (unsigned)hi*16;
    unsigned koff = A_K + (unsigned)l31*400 + (unsigned)ahl*96 + (unsigned)hi*16;
    #pragma unroll
    for (int ks = 0; ks < 3; ++ks){
      bf8t a  = *(const bf8t*)(sm + aoff + ks*32);
      bf8t b0 = *(const bf8t*)(sm + koff + ks*32);
      bf8t b1 = *(const bf8t*)(sm + koff + 32u*400 + ks*32);
      s0 = __builtin_amdgcn_mfma_f32_32x32x16_bf16(a, b0, s0, 0, 0, 0);
      s1 = __builtin_amdgcn_mfma_f32_32x32x16_bf16(a, b1, s1, 0, 0, 0);
    }
  }
  __syncthreads();   // Q/K reads done -> P may overwrite
  if (act){
    const bool m1 = (l31 >= 18);   // key 32+l31 >= 50
    unsigned pb = (unsigned)w*A_PBLK;
    float rinv[16];
    #pragma unroll
    for (int r = 0; r < 16; ++r){
      int lrow = (r&3) + 8*(r>>2) + 4*hi;
      float v0 = s0[r]*rscale;
      float v1 = m1 ? -INFINITY : s1[r]*rscale;
      float mx = fmaxf(v0, v1);
      #pragma unroll
      for (int off = 1; off <= 16; off <<= 1) mx = fmaxf(mx, __shfl_xor(mx, off));
      float e0 = __expf(v0 - mx);
      float e1 = m1 ? 0.f : __expf(v1 - mx);
      float sum = e0 + e1;
      #pragma unroll
      for (int off = 1; off <= 16; off <<= 1) sum += __shfl_xor(sum, off);
      rinv[r] = 1.0f/sum;
      *(unsigned short*)(sm + pb + (unsigned)lrow*144 + (unsigned)l31*2)      = f2bf(e0);
      *(unsigned short*)(sm + pb + (unsigned)lrow*144 + 64 + (unsigned)l31*2) = f2bf(e1);
    }
    f16t c = zero16();
    unsigned pa  = pb + (unsigned)l31*144 + (unsigned)hi*16;
    unsigned vb2 = A_VT + (unsigned)(ahl*HD + l31)*144 + (unsigned)hi*16;
    #pragma unroll
    for (int ks = 0; ks < 4; ++ks){
      bf8t a = *(const bf8t*)(sm + pa + ks*32);
      bf8t v = *(const bf8t*)(sm + vb2 + ks*32);
      c = __builtin_amdgcn_mfma_f32_32x32x16_bf16(a, v, c, 0, 0, 0);
    }
    if (l31 < HD){
      int h = hg*4 + ahl;
      #pragma unroll
      for (int r = 0; r < 16; ++r){
        int q = rt*32 + (r&3) + 8*(r>>2) + 4*hi;
        if (q < SS)
          cg[((size_t)b*SS + q)*DD + h*HD + l31] = (short)f2bf(c[r]*rinv[r]);
      }
    }
  }
}

// ============================ K3: pooling ====================================
#define B_CTX 0
#define B_LG  41984
#define B_A2  44032
#define B_SM  44288

template<int NT, int NCTM>
__device__ __forceinline__ void gemm10(const unsigned char* sm, unsigned abase,
                                       const short* __restrict__ wt,
                                       int lane, int w, f4t (&acc)[NT][4])
{
  const int lm = lane & 15, lg = lane >> 4;
  #pragma unroll
  for (int step = 0; step < 10; ++step){
    bf8t a[4];
    #pragma unroll
    for (int rt = 0; rt < 4; ++rt)
      a[rt] = *(const bf8t*)(sm + abase + (unsigned)(rt*16 + lm)*656u + (unsigned)(step*32 + lg*8)*2u);
    #pragma unroll
    for (int t = 0; t < NT; ++t){
      int ct = w + t*8; if (ct > NCTM) ct = NCTM;
      bf8t bb = *(const bf8t*)(wt + (size_t)(ct*16 + lm)*320 + step*32 + lg*8);
      #pragma unroll
      for (int rt = 0; rt < 4; ++rt)
        acc[t][rt] = __builtin_amdgcn_mfma_f32_16x16x32_bf16(a[rt], bb, acc[t][rt], 0, 0, 0);
    }
  }
}

__global__ __launch_bounds__(512) void k3_pool(
    const short* __restrict__ cg, const short* __restrict__ wsb,
    const float* __restrict__ ba, const float* __restrict__ qa,
    float* __restrict__ out)
{
  __shared__ __align__(16) unsigned char sm[B_SM];
  const int tid  = threadIdx.x;
  const int b    = blockIdx.x;
  const int w    = tid >> 6;
  const int lane = tid & 63;
  const int lm   = lane & 15, lg = lane >> 4;
  const short* waT = wsb + WAOFF;

  for (int i = tid; i < SS*75; i += 512){
    int row = i/75, c = i - row*75;
    uint2 v = *(const uint2*)(cg + ((size_t)b*SS + row)*DD + c*4);
    *(uint2*)(sm + B_CTX + (unsigned)row*656 + (unsigned)c*8) = v;
  }
  for (int i = tid; i < SS*14; i += 512)
    *(unsigned*)(sm + B_CTX + (unsigned)(i/14)*656 + 600u + (unsigned)(i%14)*4) = 0;
  __syncthreads();

  {
    f4t accp[2][4];
    #pragma unroll
    for (int t = 0; t < 2; ++t)
      #pragma unroll
      for (int r = 0; r < 4; ++r) accp[t][r] = (f4t){0.f,0.f,0.f,0.f};
    gemm10<2,12>(sm, B_CTX, waT, lane, w, accp);
    float part[4][4];
    #pragma unroll
    for (int rt2 = 0; rt2 < 4; ++rt2)
      #pragma unroll
      for (int i = 0; i < 4; ++i) part[rt2][i] = 0.f;
    #pragma unroll
    for (int t = 0; t < 2; ++t){
      int ct = w + t*8; if (ct > 12) ct = 12;
      bool valid = (t == 0) || (w < 5);
      int col = ct*16 + lm;
      float bav = (col < QDIM) ? ba[col] : 0.f;
      float qav = (valid && col < QDIM) ? qa[col] : 0.f;
      #pragma unroll
      for (int rt2 = 0; rt2 < 4; ++rt2)
        #pragma unroll
        for (int i = 0; i < 4; ++i)
          part[rt2][i] += tanhf(accp[t][rt2][i] + bav) * qav;
    }
    #pragma unroll
    for (int off = 1; off <= 8; off <<= 1)
      #pragma unroll
      for (int rt2 = 0; rt2 < 4; ++rt2)
        #pragma unroll
        for (int i = 0; i < 4; ++i)
          part[rt2][i] += __shfl_xor(part[rt2][i], off);
    if (lm == 0){
      #pragma unroll
      for (int rt2 = 0; rt2 < 4; ++rt2)
        #pragma unroll
        for (int i = 0; i < 4; ++i){
          int row = rt2*16 + lg*4 + i;
          if (row < SS) *(float*)(sm + B_LG + (unsigned)(row*8 + w)*4) = part[rt2][i];
        }
    }
  }
  __syncthreads();
  if (w == 0){
    const int sl = lane < SS ? lane : SS - 1;
    const bool rowok = lane < SS;
    float lgv = -INFINITY;
    if (rowok){
      float s = 0.f;
      #pragma unroll
      for (int j = 0; j < 8; ++j) s += *(const float*)(sm + B_LG + (unsigned)(sl*8 + j)*4);
      lgv = s;
    }
    float m = lgv;
    #pragma unroll
    for (int off = 32; off; off >>= 1) m = fmaxf(m, __shfl_xor(m, off));
    float e = rowok ? __expf(lgv - m) : 0.f;
    float ssum = e;
    #pragma unroll
    for (int off = 32; off; off >>= 1) ssum += __shfl_xor(ssum, off);
    *(float*)(sm + B_A2 + lane*4) = e / ssum;
  }
  __syncthreads();
  if (tid < DD){
    float accv = 0.f;
    for (int s = 0; s < SS; ++s){
      float av = *(const float*)(sm + B_A2 + (unsigned)s*4);
      unsigned short cv = *(const unsigned short*)(sm + B_CTX + (unsigned)s*656 + (unsigned)tid*2);
      accv = fmaf(av, __uint_as_float((unsigned)cv << 16), accv);
    }
    out[(size_t)b*DD + tid] = accv;
  }
}

// ===================== fallback: round-4 fused kernel ========================
#define OFF_UV  0
#define OFF_UE  32800
#define QKSTR   400
#define OFF_Q   65600
#define OFF_K   85600
#define OFF_P   65600
#define PBLK    4608
#define PSTR    144
#define VTSTR   144
#define OFF_VT  105600
#define OFF_CTX 117120
#define OFF_LG  159104
#define OFF_A2  161152
#define OFF_IDS 161408
#define SM_TOTAL 161616

__global__ __launch_bounds__(512) void user_enc_kernel(
    const int*   __restrict__ ids, const float* __restrict__ uv,
    const float* __restrict__ emb,
    const float* __restrict__ bq, const float* __restrict__ bk,
    const float* __restrict__ bv, const float* __restrict__ bqp,
    const float* __restrict__ bkp,
    const float* __restrict__ ba, const float* __restrict__ qa,
    const short* __restrict__ wsb, float* __restrict__ out)
{
  __shared__ __align__(16) unsigned char sm[SM_TOTAL];
  const int tid  = threadIdx.x;
  const int b    = blockIdx.x;
  const int w    = tid >> 6;
  const int lane = tid & 63;
  const int lm   = lane & 15, lg = lane >> 4;
  const int l31  = lane & 31, hi = lane >> 5;

  const short* wqT  = wsb;
  const short* wkT  = wsb + WSEG;
  const short* wvT  = wsb + 2*WSEG;
  const short* wqpT = wsb + 3*WSEG;
  const short* wkpT = wsb + 4*WSEG;
  const short* waT  = wsb + WAOFF;

  if (tid < SS) *(int*)(sm + OFF_IDS + tid*4) = ids[(size_t)b*SS + tid];
  {
    const float* srcv = uv + (size_t)b*SS*DD;
    for (int i = tid; i < SS*75; i += 512){
      int s = i/75, j4 = i - s*75;
      float4 v = *(const float4*)(srcv + s*DD + j4*4);
      *(unsigned*)(sm + OFF_UV + (unsigned)s*656 + (unsigned)j4*8)     = packbf(v.x, v.y);
      *(unsigned*)(sm + OFF_UV + (unsigned)s*656 + (unsigned)j4*8 + 4) = packbf(v.z, v.w);
    }
    for (int i = tid; i < SS*28; i += 512){
      int s = i/28, j = i - s*28;
      unsigned off = (j < 14) ? (OFF_UV + (unsigned)s*656 + 600u + (unsigned)j*4)
                              : (OFF_UE + (unsigned)s*656 + 600u + (unsigned)(j-14)*4);
      *(unsigned*)(sm + off) = 0;
    }
    for (int i = tid; i < SS*14; i += 512)
      *(unsigned*)(sm + OFF_CTX + (unsigned)(i/14)*656 + 600u + (unsigned)(i%14)*4) = 0;
    for (int i = tid; i < 720; i += 512)
      *(float4*)(sm + OFF_VT + (unsigned)i*16) = make_float4(0.f,0.f,0.f,0.f);
  }
  __syncthreads();
  for (int i = tid; i < SS*75; i += 512){
    int s = i/75, j4 = i - s*75;
    int id = *(const int*)(sm + OFF_IDS + s*4);
    float4 v = *(const float4*)(emb + (size_t)id*DD + j4*4);
    *(unsigned*)(sm + OFF_UE + (unsigned)s*656 + (unsigned)j4*8)     = packbf(v.x, v.y);
    *(unsigned*)(sm + OFF_UE + (unsigned)s*656 + (unsigned)j4*8 + 4) = packbf(v.z, v.w);
  }

  const float rscale = 0.1290994449f;
  #pragma unroll 1
  for (int nb4 = 0; nb4 < 4; ++nb4){
    const int nheads = (nb4 < 3) ? 4 : 3;
    const int NCT    = (nb4 < 3) ? 5 : 4;
    __syncthreads();
    for (int i = tid; i < SS*4; i += 512){
      int r = i >> 2, hl0 = i & 3;
      *(float4*)(sm + OFF_Q + (unsigned)r*QKSTR + (unsigned)hl0*96 + 80) = make_float4(0.f,0.f,0.f,0.f);
      *(float4*)(sm + OFF_K + (unsigned)r*QKSTR + (unsigned)hl0*96 + 80) = make_float4(0.f,0.f,0.f,0.f);
    }
    for (int ht = w; ht < 8*NCT; ht += 8){
      const int g   = (ht >= 6*NCT) ? 3 : (ht >= 4*NCT) ? 2 : (ht >= 2*NCT) ? 1 : 0;
      const int rem = ht - g*2*NCT;
      const int c   = rem >> 1, rh = rem & 1;
      const int col = nb4*80 + c*16 + lm;
      const int colc = (col < DD) ? col : DD-1;
      const int head = col / HD;
      const int dd   = col - head*HD;
      const int hl   = head - nb4*4;
      const bool valid = (hl < nheads) && (col < DD);
      const unsigned abase = (g == 1) ? (unsigned)OFF_UE : (unsigned)OFF_UV;
      const short* wt = (g==0) ? wqT : (g==1) ? wqpT : (g==2) ? wvT : wkT;
      const short* wb = wt + (size_t)col*320 + lg*8;
      f4t a0 = {0.f,0.f,0.f,0.f}, a1 = {0.f,0.f,0.f,0.f};
      #pragma unroll
      for (int st = 0; st < 10; ++st){
        bf8t bb = *(const bf8t*)(wb + st*32);
        bf8t x0 = *(const bf8t*)(sm + abase + (unsigned)(rh*32 + lm)*656u + (unsigned)(st*32 + lg*8)*2u);
        bf8t x1 = *(const bf8t*)(sm + abase + (unsigned)(rh*32 + 16 + lm)*656u + (unsigned)(st*32 + lg*8)*2u);
        a0 = __builtin_amdgcn_mfma_f32_16x16x32_bf16(x0, bb, a0, 0, 0, 0);
        a1 = __builtin_amdgcn_mfma_f32_16x16x32_bf16(x1, bb, a1, 0, 0, 0);
      }
      if (g == 2){
        if (valid){
          float bias = bv[colc];
          unsigned vb = OFF_VT + (unsigned)(hl*HD + dd)*VTSTR;
          int r0 = rh*32 + lg*4;
          if (r0 < SS){
            *(unsigned*)(sm + vb + (unsigned)r0*2) = packbf(a0[0]+bias, a0[1]+bias);
            if (r0+2 < SS) *(unsigned*)(sm + vb + (unsigned)r0*2 + 4) = packbf(a0[2]+bias, a0[3]+bias);
          }
          int r1 = rh*32 + 16 + lg*4;
          if (r1 < SS){
            *(unsigned*)(sm + vb + (unsigned)r1*2) = packbf(a1[0]+bias, a1[1]+bias);
            if (r1+2 < SS) *(unsigned*)(sm + vb + (unsigned)r1*2 + 4) = packbf(a1[2]+bias, a1[3]+bias);
          }
        }
      } else if (g != 3){
        if (valid){
          float bias = (g==0) ? bq[colc] : bqp[colc];
          unsigned qb = OFF_Q + (unsigned)hl*96 + (unsigned)dd*2 + (g==1 ? 40u : 0u);
          #pragma unroll
          for (int i = 0; i < 4; ++i){
            int r0 = rh*32 + lg*4 + i;
            if (r0 < SS) *(unsigned short*)(sm + qb + (unsigned)r0*QKSTR) = f2bf(a0[i]+bias);
            int r1 = rh*32 + 16 + lg*4 + i;
            if (r1 < SS) *(unsigned short*)(sm + qb + (unsigned)r1*QKSTR) = f2bf(a1[i]+bias);
          }
        }
      } else {
        float bkc = bk[colc];
        if (valid){
          unsigned kb = OFF_K + (unsigned)hl*96 + (unsigned)dd*2 + 40u;
          #pragma unroll
          for (int i = 0; i < 4; ++i){
            int r0 = rh*32 + lg*4 + i;
            if (r0 < SS) *(unsigned short*)(sm + kb + (unsigned)r0*QKSTR) = f2bf(a0[i]+bkc);
            int r1 = rh*32 + 16 + lg*4 + i;
            if (r1 < SS) *(unsigned short*)(sm + kb + (unsigned)r1*QKSTR) = f2bf(a1[i]+bkc);
          }
        }
        const short* wb2 = wkpT + (size_t)col*320 + lg*8;
        #pragma unroll
        for (int st = 0; st < 10; ++st){
          bf8t bb = *(const bf8t*)(wb2 + st*32);
          bf8t x0 = *(const bf8t*)(sm + OFF_UE + (unsigned)(rh*32 + lm)*656u + (unsigned)(st*32 + lg*8)*2u);
          bf8t x1 = *(const bf8t*)(sm + OFF_UE + (unsigned)(rh*32 + 16 + lm)*656u + (unsigned)(st*32 + lg*8)*2u);
          a0 = __builtin_amdgcn_mfma_f32_16x16x32_bf16(x0, bb, a0, 0, 0, 0);
          a1 = __builtin_amdgcn_mfma_f32_16x16x32_bf16(x1, bb, a1, 0, 0, 0);
        }
        if (valid){
          float bsum = bkc + bkp[colc];
          unsigned kb = OFF_K + (unsigned)hl*96 + (unsigned)dd*2;
          #pragma unroll
          for (int i = 0; i < 4; ++i){
            int r0 = rh*32 + lg*4 + i;
            if (r0 < SS) *(unsigned short*)(sm + kb + (unsigned)r0*QKSTR) = f2bf(a0[i]+bsum);
            int r1 = rh*32 + 16 + lg*4 + i;
            if (r1 < SS) *(unsigned short*)(sm + kb + (unsigned)r1*QKSTR) = f2bf(a1[i]+bsum);
          }
        }
      }
    }
    __syncthreads();
    const int ahl = w >> 1, rt = w & 1;
    const bool act = (ahl < nheads);
    f16t s0, s1;
    if (act){
      s0 = zero16(); s1 = zero16();
      unsigned aoff = OFF_Q + (unsigned)(rt*32 + l31)*QKSTR + (unsigned)ahl*96 + (unsigned)hi*16;
      unsigned koff = OFF_K + (unsigned)l31*QKSTR + (unsigned)ahl*96 + (unsigned)hi*16;
      #pragma unroll
      for (int ks = 0; ks < 3; ++ks){
        bf8t a  = *(const bf8t*)(sm + aoff + ks*32);
        bf8t b0 = *(const bf8t*)(sm + koff + ks*32);
        bf8t b1 = *(const bf8t*)(sm + koff + 32u*QKSTR + ks*32);
        s0 = __builtin_amdgcn_mfma_f32_32x32x16_bf16(a, b0, s0, 0, 0, 0);
        s1 = __builtin_amdgcn_mfma_f32_32x32x16_bf16(a, b1, s1, 0, 0, 0);
      }
    }
    __syncthreads();
    if (act){
      const bool m1 = (l31 >= 18);
      unsigned pb = OFF_P + (unsigned)w*PBLK;
      float rinv[16];
      #pragma unroll
      for (int r = 0; r < 16; ++r){
        int lrow = (r&3) + 8*(r>>2) + 4*hi;
        float v0 = s0[r]*rscale;
        float v1 = m1 ? -INFINITY : s1[r]*rscale;
        float mx = fmaxf(v0, v1);
        #pragma unroll
        for (int off = 1; off <= 16; off <<= 1) mx = fmaxf(mx, __shfl_xor(mx, off));
        float e0 = __expf(v0 - mx);
        float e1 = m1 ? 0.f : __expf(v1 - mx);
        float sum = e0 + e1;
        #pragma unroll
        for (int off = 1; off <= 16; off <<= 1) sum += __shfl_xor(sum, off);
        rinv[r] = 1.0f/sum;
        *(unsigned short*)(sm + pb + (unsigned)lrow*PSTR + (unsigned)l31*2)      = f2bf(e0);
        *(unsigned short*)(sm + pb + (unsigned)lrow*PSTR + 64 + (unsigned)l31*2) = f2bf(e1);
      }
      f16t c = zero16();
      unsigned pa  = pb + (unsigned)l31*PSTR + (unsigned)hi*16;
      unsigned vb2 = OFF_VT + (unsigned)(ahl*HD + l31)*VTSTR + (unsigned)hi*16;
      #pragma unroll
      for (int ks = 0; ks < 4; ++ks){
        bf8t a = *(const bf8t*)(sm + pa + ks*32);
        bf8t v = *(const bf8t*)(sm + vb2 + ks*32);
        c = __builtin_amdgcn_mfma_f32_32x32x16_bf16(a, v, c, 0, 0, 0);
      }
      if (l31 < HD){
        int h = nb4*4 + ahl;
        #pragma unroll
        for (int r = 0; r < 16; ++r){
          int q = rt*32 + (r&3) + 8*(r>>2) + 4*hi;
          if (q < SS)
            *(unsigned short*)(sm + OFF_CTX + (unsigned)q*656 + (unsigned)(h*HD + l31)*2) =
                f2bf(c[r]*rinv[r]);
        }
      }
    }
  }
  __syncthreads();

  {
    f4t accp[2][4];
    #pragma unroll
    for (int t = 0; t < 2; ++t)
      #pragma unroll
      for (int r = 0; r < 4; ++r) accp[t][r] = (f4t){0.f,0.f,0.f,0.f};
    gemm10<2,12>(sm, OFF_CTX, waT, lane, w, accp);
    float part[4][4];
    #pragma unroll
    for (int rt2 = 0; rt2 < 4; ++rt2)
      #pragma unroll
      for (int i = 0; i < 4; ++i) part[rt2][i] = 0.f;
    #pragma unroll
    for (int t = 0; t < 2; ++t){
      int ct = w + t*8; if (ct > 12) ct = 12;
      bool valid = (t == 0) || (w < 5);
      int col = ct*16 + lm;
      float bav = (col < QDIM) ? ba[col] : 0.f;
      float qav = (valid && col < QDIM) ? qa[col] : 0.f;
      #pragma unroll
      for (int rt2 = 0; rt2 < 4; ++rt2)
        #pragma unroll
        for (int i = 0; i < 4; ++i)
          part[rt2][i] += tanhf(accp[t][rt2][i] + bav) * qav;
    }
    #pragma unroll
    for (int off = 1; off <= 8; off <<= 1)
      #pragma unroll
      for (int rt2 = 0; rt2 < 4; ++rt2)
        #pragma unroll
        for (int i = 0; i < 4; ++i)
          part[rt2][i] += __shfl_xor(part[rt2][i], off);
    if (lm == 0){
      #pragma unroll
      for (int rt2 = 0; rt2 < 4; ++rt2)
        #pragma unroll
        for (int i = 0; i < 4; ++i){
          int row = rt2*16 + lg*4 + i;
          if (row < SS) *(float*)(sm + OFF_LG + (unsigned)(row*8 + w)*4) = part[rt2][i];
        }
    }
  }
  __syncthreads();
  if (w == 0){
    const int sl = lane < SS ? lane : SS - 1;
    const bool rowok = lane < SS;
    float lgv = -INFINITY;
    if (rowok){
      float s = 0.f;
      #pragma unroll
      for (int j = 0; j < 8; ++j) s += *(const float*)(sm + OFF_LG + (unsigned)(sl*8 + j)*4);
      lgv = s;
    }
    float m = lgv;
    #pragma unroll
    for (int off = 32; off; off >>= 1) m = fmaxf(m, __shfl_xor(m, off));
    float e = rowok ? __expf(lgv - m) : 0.f;
    float ssum = e;
    #pragma unroll
    for (int off = 32; off; off >>= 1) ssum += __shfl_xor(ssum, off);
    *(float*)(sm + OFF_A2 + lane*4) = e / ssum;
  }
  __syncthreads();
  if (tid < DD){
    float accv = 0.f;
    for (int s = 0; s < SS; ++s){
      float av = *(const float*)(sm + OFF_A2 + (unsigned)s*4);
      unsigned short cv = *(const unsigned short*)(sm + OFF_CTX + (unsigned)s*656 + (unsigned)tid*2);
      accv = fmaf(av, __uint_as_float((unsigned)cv << 16), accv);
    }
    out[(size_t)b*DD + tid] = accv;
  }
}

extern "C" void kernel_launch(void* const* d_in, const int* in_sizes, int n_in,
                              void* d_out, int out_size, void* d_ws, size_t ws_size,
                              hipStream_t stream){
  (void)n_in; (void)out_size;
  const int*   ids = (const int*)  d_in[0];
  const float* uvp = (const float*)d_in[1];
  const float* emb = (const float*)d_in[2];
  const float* Wq  = (const float*)d_in[3];
  const float* bq  = (const float*)d_in[4];
  const float* Wk  = (const float*)d_in[5];
  const float* bk  = (const float*)d_in[6];
  const float* Wv  = (const float*)d_in[7];
  const float* bv  = (const float*)d_in[8];
  const float* Wqp = (const float*)d_in[9];
  const float* bqp = (const float*)d_in[10];
  const float* Wkp = (const float*)d_in[11];
  const float* bkp = (const float*)d_in[12];
  const float* Wa  = (const float*)d_in[13];
  const float* ba  = (const float*)d_in[14];
  const float* qa  = (const float*)d_in[15];
  short* wsb = (short*)d_ws;

  const int nb = in_sizes[0] / SS;   // 1024
  const int M  = nb * SS;            // 51200
  const int mtiles = (M + 255) / 256; // 200 (divisible by 8 -> bijective map)

  // ws layouts (bf16 elems):
  //   with a1:    weights | a1 [M][320] | a2 [M][320] | 5 x C [M][300]
  //   without a1: weights |               a2 [M][320] | 5 x C [M][300]
  const size_t AELEM = (size_t)M * 320;
  const size_t CELEM = (size_t)M * DD;
  const size_t needA = (WTOT + 2*AELEM + 5*CELEM) * 2;
  const size_t needB = (WTOT +   AELEM + 5*CELEM) * 2;

  conv_weights<<<(WTOT + 255)/256, 256, 0, stream>>>(Wq, Wk, Wv, Wqp, Wkp, Wa, wsb);

  if (ws_size >= needB){
    const bool hasA1 = (ws_size >= needA);
    short* a1  = hasA1 ? (wsb + WTOT) : nullptr;
    short* a2  = wsb + WTOT + (hasA1 ? AELEM : 0);
    short* qcg = a2 + AELEM;
    short* kcg = qcg + CELEM;
    short* vg  = kcg + CELEM;
    short* qpg = vg  + CELEM;
    short* kpg = qpg + CELEM;
    short* cg  = a2;   // alias: a2 dead after k1

    k0_gather<<<nb, 512, 0, stream>>>(ids, emb, a2);
    if (hasA1) k0b_conv<<<2048, 512, 0, stream>>>(uvp, a1, M);
    k1_gemm<<<25*mtiles, 512, 0, stream>>>(uvp, (const short*)a1, (const short*)a2,
                                           (const short*)wsb,
                                           bq, bk, bv, bqp, bkp,
                                           qcg, kcg, vg, qpg, kpg, mtiles, M);
    k2_attn<<<nb*4, 512, 0, stream>>>((const short*)qcg, (const short*)qpg,
                                      (const short*)kcg, (const short*)kpg,
                                      (const short*)vg, cg);
    k3_pool<<<nb, 512, 0, stream>>>((const short*)cg, (const short*)wsb,
                                    ba, qa, (float*)d_out);
  } else {
    user_enc_kernel<<<nb, 512, 0, stream>>>(ids, uvp, emb,
                                            bq, bk, bv, bqp, bkp, ba, qa,
                                            (const short*)wsb, (float*)d_out);
  }
}